// Round 14
// baseline (277.069 us; speedup 1.0000x reference)
//
#include <hip/hip_runtime.h>
#include <hip/hip_bf16.h>
#include <math.h>

#define N_NODES 16384
#define E_EDGES 131072
#define ETOT (E_EDGES + N_NODES)   // 147456 (self-loops appended)
#define BGRAPH 256
#define F_INPUT 78
#define KPAD1 96                   // F_INPUT padded to mult of 32
#define HID 128
#define HEADS 10
#define F1 (HEADS * HID)           // 1280
#define F_CELL 954
#define KPADC 960                  // F_CELL padded
#define NEG_SLOPE 0.2f

typedef __attribute__((ext_vector_type(8))) short frag_t;   // 8 bf16
typedef __attribute__((ext_vector_type(4))) float f4_t;

static __device__ __forceinline__ unsigned fkey(float f) {
    unsigned b = __float_as_uint(f);
    return (b & 0x80000000u) ? ~b : (b | 0x80000000u);
}
static __device__ __forceinline__ float funkey(unsigned k) {
    unsigned b = (k & 0x80000000u) ? (k ^ 0x80000000u) : ~k;
    return __uint_as_float(b);
}
static __device__ __forceinline__ unsigned short f2bf(float f) {
    __hip_bfloat16 h = __float2bfloat16(f);
    return *(unsigned short*)&h;
}
static __device__ __forceinline__ float bf2f(unsigned short u) {
    return __uint_as_float(((unsigned)u) << 16);
}

// ======== gemm_db: 2-phase double-buffered MFMA GEMM (reg prefetch) ============
// OUT_MODE: 0 = f32 store, 1 = bf16 store,
//           2 = coef1 scatter (cols 0..9 -> esp, 16..25 -> edp)
// ACT: 0 none, 1 relu, 2 elu.
template<int WM16, int WN16, int OUT_MODE, int ACT, int HAS_BIAS>
__global__ __launch_bounds__(256) void gemm_db(
    const unsigned short* __restrict__ A, const unsigned short* __restrict__ BT,
    const float* __restrict__ bias, void* __restrict__ C,
    float* __restrict__ esp, float* __restrict__ edp,
    int M, int N, int K, int lda, int ldb, int ldc,
    int za, int zb, int zc, int zbias)
{
    constexpr int BM = 32 * WM16, BN = 32 * WN16;
    constexpr int LA = BM * 4;
    constexpr int LB = BN * 4;
    constexpr int NA = (LA + 255) / 256;
    constexpr int NB = (LB + 255) / 256;
    __shared__ __align__(16) unsigned short Als[2][BM * 32];
    __shared__ __align__(16) unsigned short Bls[2][BN * 32];
    const int z = blockIdx.z;
    A  += (size_t)z * za;
    BT += (size_t)z * zb;
    const int t = threadIdx.x;
    const int wave = t >> 6, lane = t & 63;
    const int wr = (wave >> 1) * (16 * WM16);
    const int wc = (wave & 1) * (16 * WN16);
    const int row0 = blockIdx.y * BM;
    const int col0 = blockIdx.x * BN;
    const int lrow = lane & 15, kg = lane >> 4;

    uint4 pa[NA], pb[NB];
    auto LOAD = [&](int kk) {
#pragma unroll
        for (int i = 0; i < NA; i++) { int idx = t + i * 256; if (idx < LA) {
            int r = idx >> 2, sl = idx & 3;
            pa[i] = *(const uint4*)&A[(size_t)(row0 + r) * lda + kk + sl * 8]; } }
#pragma unroll
        for (int i = 0; i < NB; i++) { int idx = t + i * 256; if (idx < LB) {
            int r = idx >> 2, sl = idx & 3;
            pb[i] = *(const uint4*)&BT[(size_t)(col0 + r) * ldb + kk + sl * 8]; } }
    };
    auto STORE = [&](int buf) {
#pragma unroll
        for (int i = 0; i < NA; i++) { int idx = t + i * 256; if (idx < LA) {
            int r = idx >> 2, sl = idx & 3;
            *(uint4*)&Als[buf][r * 32 + ((sl ^ (r & 3) ^ ((r >> 2) & 3)) * 8)] = pa[i]; } }
#pragma unroll
        for (int i = 0; i < NB; i++) { int idx = t + i * 256; if (idx < LB) {
            int r = idx >> 2, sl = idx & 3;
            *(uint4*)&Bls[buf][r * 32 + ((sl ^ (r & 3) ^ ((r >> 2) & 3)) * 8)] = pb[i]; } }
    };

    f4_t acc[WM16][WN16];
#pragma unroll
    for (int m = 0; m < WM16; m++)
#pragma unroll
        for (int n = 0; n < WN16; n++) acc[m][n] = (f4_t){0.f, 0.f, 0.f, 0.f};

    LOAD(0);
    STORE(0);
    __syncthreads();

    const int nk = K / 32;
    int cur = 0;
    for (int ks = 0; ks < nk; ks++) {
        if (ks < nk - 1) LOAD((ks + 1) * 32);
        frag_t af[WM16], bfr[WN16];
#pragma unroll
        for (int m = 0; m < WM16; m++) {
            int r = wr + m * 16 + lrow;
            af[m] = *(frag_t*)&Als[cur][r * 32 + ((kg ^ (r & 3) ^ ((r >> 2) & 3)) * 8)];
        }
#pragma unroll
        for (int n = 0; n < WN16; n++) {
            int r = wc + n * 16 + lrow;
            bfr[n] = *(frag_t*)&Bls[cur][r * 32 + ((kg ^ (r & 3) ^ ((r >> 2) & 3)) * 8)];
        }
#pragma unroll
        for (int m = 0; m < WM16; m++)
#pragma unroll
            for (int n = 0; n < WN16; n++)
                acc[m][n] = __builtin_amdgcn_mfma_f32_16x16x32_bf16(af[m], bfr[n], acc[m][n], 0, 0, 0);
        if (ks < nk - 1) STORE(cur ^ 1);
        __syncthreads();
        cur ^= 1;
    }

#pragma unroll
    for (int m = 0; m < WM16; m++) {
#pragma unroll
        for (int n = 0; n < WN16; n++) {
            int col = col0 + wc + n * 16 + lrow;
            float bv = HAS_BIAS ? bias[z * zbias + col] : 0.f;
#pragma unroll
            for (int r = 0; r < 4; r++) {
                int row = row0 + wr + m * 16 + kg * 4 + r;
                float v = acc[m][n][r] + bv;
                if (ACT == 1) v = fmaxf(v, 0.f);
                if (ACT == 2) v = (v > 0.f) ? v : expm1f(v);
                size_t ci = (size_t)row * ldc + (size_t)z * zc + col;
                if (OUT_MODE == 0)      ((float*)C)[ci] = v;
                else if (OUT_MODE == 1) ((unsigned short*)C)[ci] = f2bf(v);
                else {
                    if (col < 10)                  esp[row * 10 + col] = v;
                    else if (col >= 16 && col < 26) edp[row * 10 + (col - 16)] = v;
                }
            }
        }
    }
}

// ================= single-buffered template (small GEMMs: steps 10, 13) ========
// OUT_MODE: 0 = f32 store, 4 = row-reduce with ca=[N][2] -> C[row*ldc+128/129]+cd
template<int WM16, int WN16, int OUT_MODE, int ACT, int HAS_BIAS>
__global__ __launch_bounds__(256) void mfma_gemm(
    const unsigned short* __restrict__ A, const unsigned short* __restrict__ BT,
    const float* __restrict__ bias, void* __restrict__ C,
    const float* __restrict__ ca, const float* __restrict__ cd,
    int M, int N, int Kpad, int lda, int ldb, int ldc)
{
    constexpr int BM = 32 * WM16, BN = 32 * WN16;
    __shared__ __align__(16) unsigned short Als[BM * 32];
    __shared__ __align__(16) unsigned short Bls[BN * 32];
    const int t = threadIdx.x;
    const int wave = t >> 6, lane = t & 63;
    const int wr = (wave >> 1) * (16 * WM16);
    const int wc = (wave & 1) * (16 * WN16);
    const int row0 = blockIdx.y * BM;
    const int col0 = blockIdx.x * BN;

    f4_t acc[WM16][WN16];
#pragma unroll
    for (int m = 0; m < WM16; m++)
#pragma unroll
        for (int n = 0; n < WN16; n++) { acc[m][n] = (f4_t){0.f, 0.f, 0.f, 0.f}; }

    const int lrow = lane & 15, kg = lane >> 4;
    for (int kk = 0; kk < Kpad; kk += 32) {
        for (int i = t; i < BM * 4; i += 256) {
            int r = i >> 2, slot = i & 3;
            uint4 v = *(const uint4*)&A[(size_t)(row0 + r) * lda + kk + slot * 8];
            *(uint4*)&Als[r * 32 + ((slot ^ (r & 3) ^ ((r >> 2) & 3)) * 8)] = v;
        }
        for (int i = t; i < BN * 4; i += 256) {
            int r = i >> 2, slot = i & 3;
            uint4 v = *(const uint4*)&BT[(size_t)(col0 + r) * ldb + kk + slot * 8];
            *(uint4*)&Bls[r * 32 + ((slot ^ (r & 3) ^ ((r >> 2) & 3)) * 8)] = v;
        }
        __syncthreads();
        frag_t af[WM16], bfr[WN16];
#pragma unroll
        for (int m = 0; m < WM16; m++) {
            int r = wr + m * 16 + lrow;
            af[m] = *(frag_t*)&Als[r * 32 + ((kg ^ (r & 3) ^ ((r >> 2) & 3)) * 8)];
        }
#pragma unroll
        for (int n = 0; n < WN16; n++) {
            int r = wc + n * 16 + lrow;
            bfr[n] = *(frag_t*)&Bls[r * 32 + ((kg ^ (r & 3) ^ ((r >> 2) & 3)) * 8)];
        }
#pragma unroll
        for (int m = 0; m < WM16; m++)
#pragma unroll
            for (int n = 0; n < WN16; n++)
                acc[m][n] = __builtin_amdgcn_mfma_f32_16x16x32_bf16(af[m], bfr[n], acc[m][n], 0, 0, 0);
        __syncthreads();
    }

    if constexpr (OUT_MODE == 0) {
#pragma unroll
        for (int m = 0; m < WM16; m++) {
#pragma unroll
            for (int n = 0; n < WN16; n++) {
                int col = col0 + wc + n * 16 + lrow;
                float bv = HAS_BIAS ? bias[col] : 0.f;
#pragma unroll
                for (int r = 0; r < 4; r++) {
                    int row = row0 + wr + m * 16 + kg * 4 + r;
                    float v = acc[m][n][r] + bv;
                    if (ACT == 1) v = fmaxf(v, 0.f);
                    ((float*)C)[(size_t)row * ldc + col] = v;
                }
            }
        }
    } else {
        __shared__ float o2l[BM][2];
        if (t < BM) { o2l[t][0] = 0.f; o2l[t][1] = 0.f; }
        __syncthreads();
#pragma unroll
        for (int m = 0; m < WM16; m++) {
#pragma unroll
            for (int r = 0; r < 4; r++) {
                int lr = wr + m * 16 + kg * 4 + r;
                float p0 = 0.f, p1 = 0.f;
#pragma unroll
                for (int n = 0; n < WN16; n++) {
                    int col = col0 + wc + n * 16 + lrow;
                    float v = acc[m][n][r] + (HAS_BIAS ? bias[col] : 0.f);
                    if (ACT == 1) v = fmaxf(v, 0.f);
                    p0 = fmaf(v, ca[col * 2], p0);
                    p1 = fmaf(v, ca[col * 2 + 1], p1);
                }
                atomicAdd(&o2l[lr][0], p0);
                atomicAdd(&o2l[lr][1], p1);
            }
        }
        __syncthreads();
        if (t < BM) {
            ((float*)C)[(size_t)(row0 + t) * ldc + 128] = o2l[t][0] + cd[0];
            ((float*)C)[(size_t)(row0 + t) * ldc + 129] = o2l[t][1] + cd[1];
        }
    }
}

// ===== w1h2_fused: H2 = sum_h elu(agg_h @ W1_h + b1_h) @ W2_h, x1 never hits HBM
// Block = 64 rows, 4 waves (2x2: wr in {0,32}, wc in {0,64}). Per head:
//   phase A: stage agg_h[64,96] + W1_h[128,96] -> GEMM1 (K=96) -> acc1
//   phase B: elu(acc1+b1) -> LDS x1h [4ks][64][32] swizzled; stage W2_h[128,128]
//            -> GEMM2 (K=128) accumulates acc2
// Epilogue: wide-store bf16 H2 + fused es2/ed2 row-dots. LDS pool 48KB -> 3/CU.
__global__ __launch_bounds__(256) void w1h2_fused(
    const unsigned short* __restrict__ aggb,   // [N,960] bf16
    const unsigned short* __restrict__ W1T,    // [1280,96] bf16
    const float* __restrict__ b1,              // [1280]
    const unsigned short* __restrict__ W2T,    // [128,1280] bf16
    unsigned short* __restrict__ H2,           // [N,128] bf16
    const float* __restrict__ as2, const float* __restrict__ ad2,
    float* __restrict__ es2, float* __restrict__ ed2)
{
    __shared__ __align__(16) unsigned short ls[24576];   // 48 KB pool
    __shared__ float esl[2][64], edl[2][64];
    const int t = threadIdx.x;
    const int wave = t >> 6, lane = t & 63;
    const int lrow = lane & 15, kg = lane >> 4;
    const int row0 = blockIdx.x * 64;
    const int wr = (wave >> 1) * 32;
    const int wcol = wave & 1;
    const int wc = wcol * 64;

    f4_t acc2[2][4];
#pragma unroll
    for (int m = 0; m < 2; m++)
#pragma unroll
        for (int n = 0; n < 4; n++) acc2[m][n] = (f4_t){0.f, 0.f, 0.f, 0.f};

    for (int h = 0; h < HEADS; h++) {
        // ---- phase A staging: agg_h at [0,6144), W1_h at [6144,18432) ----
        for (int i = t; i < 768; i += 256) {
            int r = i / 12, c = i % 12;
            int ks = c >> 2, sl = c & 3;
            uint4 v = *(const uint4*)&aggb[(size_t)(row0 + r) * 960 + h * 96 + ks * 32 + sl * 8];
            *(uint4*)&ls[(ks * 64 + r) * 32 + ((sl ^ (r & 3) ^ ((r >> 2) & 3)) * 8)] = v;
        }
        for (int i = t; i < 1536; i += 256) {
            int r = i / 12, c = i % 12;
            int ks = c >> 2, sl = c & 3;
            uint4 v = *(const uint4*)&W1T[(size_t)(h * 128 + r) * 96 + ks * 32 + sl * 8];
            *(uint4*)&ls[6144 + (ks * 128 + r) * 32 + ((sl ^ (r & 3) ^ ((r >> 2) & 3)) * 8)] = v;
        }
        __syncthreads();

        // ---- GEMM1: acc1 = agg_h @ W1_h (K=96) ----
        f4_t acc1[2][4];
#pragma unroll
        for (int m = 0; m < 2; m++)
#pragma unroll
            for (int n = 0; n < 4; n++) acc1[m][n] = (f4_t){0.f, 0.f, 0.f, 0.f};
#pragma unroll
        for (int ks = 0; ks < 3; ks++) {
            frag_t af[2], bfr[4];
#pragma unroll
            for (int m = 0; m < 2; m++) {
                int r = wr + m * 16 + lrow;
                af[m] = *(frag_t*)&ls[(ks * 64 + r) * 32 + ((kg ^ (r & 3) ^ ((r >> 2) & 3)) * 8)];
            }
#pragma unroll
            for (int n = 0; n < 4; n++) {
                int r = wc + n * 16 + lrow;
                bfr[n] = *(frag_t*)&ls[6144 + (ks * 128 + r) * 32 + ((kg ^ (r & 3) ^ ((r >> 2) & 3)) * 8)];
            }
#pragma unroll
            for (int m = 0; m < 2; m++)
#pragma unroll
                for (int n = 0; n < 4; n++)
                    acc1[m][n] = __builtin_amdgcn_mfma_f32_16x16x32_bf16(af[m], bfr[n], acc1[m][n], 0, 0, 0);
        }
        __syncthreads();   // phase-A reads done; pool reusable

        // ---- phase B: x1h (elu) -> [0,8192) swizzled; W2_h -> [8192,24576) ----
#pragma unroll
        for (int m = 0; m < 2; m++) {
#pragma unroll
            for (int n = 0; n < 4; n++) {
                int col = wc + n * 16 + lrow;        // = k index of GEMM2
                float bv = b1[h * HID + col];
                int ks2 = col >> 5, cw = col & 31, slot = cw >> 3, elem = cw & 7;
#pragma unroll
                for (int r = 0; r < 4; r++) {
                    int row = wr + m * 16 + kg * 4 + r;
                    float v = acc1[m][n][r] + bv;
                    v = (v > 0.f) ? v : expm1f(v);
                    ls[(ks2 * 64 + row) * 32 + ((slot ^ (row & 3) ^ ((row >> 2) & 3)) * 8) + elem] = f2bf(v);
                }
            }
        }
        for (int i = t; i < 2048; i += 256) {
            int r = i >> 4, c = i & 15;
            int ks2 = c >> 2, sl = c & 3;
            uint4 v = *(const uint4*)&W2T[(size_t)r * F1 + h * 128 + ks2 * 32 + sl * 8];
            *(uint4*)&ls[8192 + (ks2 * 128 + r) * 32 + ((sl ^ (r & 3) ^ ((r >> 2) & 3)) * 8)] = v;
        }
        __syncthreads();

        // ---- GEMM2: acc2 += x1h @ W2_h (K=128) ----
#pragma unroll
        for (int ks = 0; ks < 4; ks++) {
            frag_t af[2], bfr[4];
#pragma unroll
            for (int m = 0; m < 2; m++) {
                int r = wr + m * 16 + lrow;
                af[m] = *(frag_t*)&ls[(ks * 64 + r) * 32 + ((kg ^ (r & 3) ^ ((r >> 2) & 3)) * 8)];
            }
#pragma unroll
            for (int n = 0; n < 4; n++) {
                int r = wc + n * 16 + lrow;
                bfr[n] = *(frag_t*)&ls[8192 + (ks * 128 + r) * 32 + ((kg ^ (r & 3) ^ ((r >> 2) & 3)) * 8)];
            }
#pragma unroll
            for (int m = 0; m < 2; m++)
#pragma unroll
                for (int n = 0; n < 4; n++)
                    acc2[m][n] = __builtin_amdgcn_mfma_f32_16x16x32_bf16(af[m], bfr[n], acc2[m][n], 0, 0, 0);
        }
        __syncthreads();   // before next head's staging overwrites pool
    }

    // ---- epilogue: stage bf16 H2 tile + es2/ed2 row dots ----
#pragma unroll
    for (int m = 0; m < 2; m++) {
#pragma unroll
        for (int r = 0; r < 4; r++) {
            int lr = wr + m * 16 + kg * 4 + r;
            float pes = 0.f, ped = 0.f;
#pragma unroll
            for (int n = 0; n < 4; n++) {
                int col = wc + n * 16 + lrow;
                float v = acc2[m][n][r];
                ls[lr * 128 + col] = f2bf(v);
                pes = fmaf(v, as2[col], pes);
                ped = fmaf(v, ad2[col], ped);
            }
#pragma unroll
            for (int o = 1; o < 16; o <<= 1) {
                pes += __shfl_xor(pes, o);
                ped += __shfl_xor(ped, o);
            }
            if (lrow == 0) { esl[wcol][lr] = pes; edl[wcol][lr] = ped; }
        }
    }
    __syncthreads();
    for (int i = t; i < 1024; i += 256) {
        int r = i >> 4, seg = i & 15;
        *(uint4*)&H2[(size_t)(row0 + r) * HID + seg * 8] = *(const uint4*)&ls[r * 128 + seg * 8];
    }
    if (t < 64) {
        es2[row0 + t] = esl[0][t] + esl[1][t];
        ed2[row0 + t] = edl[0][t] + edl[1][t];
    }
}

// ================= mega prep: converts + transposes + fold + zero-pk + hist ====
#define S0 1572864   // xb: 16384*96
#define S1 122880    // W1T: 1280*96
#define S2 163840    // W2T: 128*1280
#define S3 1966080   // Wf1T: 2048*960
#define S4 1048576   // Wf2T: 512*2048
#define S5 65536     // Wf3T: 128*512
#define S6 16384     // WgT: 128*128
#define PREP_TOTAL (S0+S1+S2+S3+S4+S5+S6)   // 4956160 = 19360*256
#define NB_ELEM (PREP_TOTAL / 256)          // 19360
#define NB_FOLD 768                          // 3072 fold entries, 4 waves/block
#define NB_ZPK  128                          // pk: 32768
#define NB_HIST ((ETOT + 255) / 256)         // 576

__global__ void prep_all(const float* __restrict__ x,  const float* __restrict__ W1,
                         const float* __restrict__ W2, const float* __restrict__ Wf1,
                         const float* __restrict__ Wf2, const float* __restrict__ Wf3,
                         const float* __restrict__ Wg,
                         const float* __restrict__ as1, const float* __restrict__ ad1,
                         const int* __restrict__ ei,
                         unsigned short* __restrict__ xb,  unsigned short* __restrict__ W1T,
                         unsigned short* __restrict__ W2T, unsigned short* __restrict__ Wf1T,
                         unsigned short* __restrict__ Wf2T, unsigned short* __restrict__ Wf3T,
                         unsigned short* __restrict__ WgT, unsigned short* __restrict__ F1T,
                         int* __restrict__ counts, unsigned* __restrict__ pk)
{
    int blk = blockIdx.x, t = threadIdx.x;
    if (blk < NB_ELEM) {
        int i = blk * 256 + t;
        if (i < S0) { int r = i / 96, k = i % 96;
            xb[i] = (k < F_INPUT) ? f2bf(x[r * F_INPUT + k]) : 0; return; }
        i -= S0;
        if (i < S1) { int n = i / 96, k = i % 96;
            W1T[i] = (k < F_INPUT) ? f2bf(W1[(size_t)k * F1 + n]) : 0; return; }
        i -= S1;
        if (i < S2) { int n = i / 1280, k = i % 1280;
            W2T[i] = f2bf(W2[(size_t)k * HID + n]); return; }
        i -= S2;
        if (i < S3) { int n = i / 960, k = i % 960;
            Wf1T[i] = (k < F_CELL) ? f2bf(Wf1[(size_t)k * 2048 + n]) : 0; return; }
        i -= S3;
        if (i < S4) { int n = i / 2048, k = i % 2048;
            Wf2T[i] = f2bf(Wf2[(size_t)k * 512 + n]); return; }
        i -= S4;
        if (i < S5) { int n = i / 512, k = i % 512;
            Wf3T[i] = f2bf(Wf3[(size_t)k * HID + n]); return; }
        i -= S5;
        { int n = i / 128, k = i % 128;
            WgT[i] = f2bf(Wg[(size_t)k * HID + n]); }
        return;
    }
    blk -= NB_ELEM;
    if (blk < NB_FOLD) {
        int idx = blk * 4 + (t >> 6);
        int l = t & 63;
        int r = idx / 96, k = idx % 96;
        int sd = r >> 4, h = r & 15;
        float p = 0.f;
        if (h < HEADS && k < F_INPUT) {
            const float* a = (sd ? ad1 : as1) + h * HID;
            float2 wv = *(const float2*)&W1[(size_t)k * F1 + h * HID + 2 * l];
            float2 av = *(const float2*)&a[2 * l];
            p = wv.x * av.x + wv.y * av.y;
#pragma unroll
            for (int o = 32; o > 0; o >>= 1) p += __shfl_xor(p, o);
        }
        if (l == 0) F1T[(size_t)r * 96 + k] = f2bf(p);
        return;
    }
    blk -= NB_FOLD;
    if (blk < NB_ZPK) { pk[blk * 256 + t] = 0; return; }   // 0 < fkey(any float)
    blk -= NB_ZPK;
    int e = blk * 256 + t;
    if (e < ETOT) {
        int dst = (e < E_EDGES) ? ei[E_EDGES + e] : (e - E_EDGES);
        atomicAdd(&counts[dst], 1);
    }
}

// ================= CSR scan (vectorized) + scatter =================
__global__ void scan_counts(const int* __restrict__ counts,
                            int* __restrict__ row_start, int* __restrict__ cursor)
{
    __shared__ int part[256];
    int t = threadIdx.x;
    int base = t * 64;
    int4 v[16];
#pragma unroll
    for (int i = 0; i < 16; i++) v[i] = *(const int4*)&counts[base + i * 4];
    int sum = 0;
#pragma unroll
    for (int i = 0; i < 16; i++) sum += v[i].x + v[i].y + v[i].z + v[i].w;
    part[t] = sum;
    __syncthreads();
    for (int o = 1; o < 256; o <<= 1) {
        int vv = (t >= o) ? part[t - o] : 0;
        __syncthreads();
        part[t] += vv;
        __syncthreads();
    }
    int run = (t == 0) ? 0 : part[t - 1];
#pragma unroll
    for (int i = 0; i < 16; i++) {
        int4 w;
        w.x = run; run += v[i].x;
        w.y = run; run += v[i].y;
        w.z = run; run += v[i].z;
        w.w = run; run += v[i].w;
        *(int4*)&row_start[base + i * 4] = w;
        *(int4*)&cursor[base + i * 4] = w;
    }
    if (t == 255) row_start[N_NODES] = run;
}

__global__ void scatter_csr(const int* __restrict__ ei, int* __restrict__ cursor,
                            int* __restrict__ csr_src)
{
    int e = blockIdx.x * blockDim.x + threadIdx.x;
    if (e >= ETOT) return;
    int src, dst;
    if (e < E_EDGES) { src = ei[e]; dst = ei[E_EDGES + e]; } else { src = dst = e - E_EDGES; }
    int pos = atomicAdd(&cursor[dst], 1);
    csr_src[pos] = src;
}

// ================= GAT layer-1 aggregation over RAW x (96 bf16 per row) ========
__global__ __launch_bounds__(256) void gat1_agg(
    const int* __restrict__ row_start, const int* __restrict__ csr_src,
    const unsigned* __restrict__ xb32,          // [N,48] u32 = 96 bf16
    const float* __restrict__ es, const float* __restrict__ ed,
    unsigned* __restrict__ aggb)                // [N,480] u32 = 960 bf16
{
    const int w = threadIdx.x >> 6, l = threadIdx.x & 63;
    const int n = blockIdx.x * 4 + w;
    const int rs = row_start[n];
    const int deg = row_start[n + 1] - rs;

    __shared__ __align__(16) float w_lds[4][64][12];
    __shared__ int src_lds[4][64];

    float edv[HEADS];
    const float* edp = ed + n * HEADS;
#pragma unroll
    for (int h = 0; h < HEADS; h++) edv[h] = edp[h];

    float acc0[HEADS], acc1[HEADS], den[HEADS];
#pragma unroll
    for (int h = 0; h < HEADS; h++) { acc0[h] = 0.f; acc1[h] = 0.f; den[h] = 0.f; }

    for (int base = 0; base < deg; base += 64) {
        int e = base + l;
        int cnt = min(64, deg - base);
        float wv[HEADS];
        if (e < deg) {
            int s = csr_src[rs + e];
            src_lds[w][l] = s;
            const float* ep = es + s * HEADS;
#pragma unroll
            for (int h = 0; h < HEADS; h++) {
                float v = ep[h] + edv[h];
                v = (v >= 0.f) ? v : NEG_SLOPE * v;
                wv[h] = __expf(v);
            }
        } else {
#pragma unroll
            for (int h = 0; h < HEADS; h++) wv[h] = 0.f;
        }
#pragma unroll
        for (int h = 0; h < HEADS; h++) {
            den[h] += wv[h];
            w_lds[w][l][h] = wv[h];
        }
        asm volatile("" ::: "memory");

        for (int j = 0; j < cnt; j++) {
            int sj = src_lds[w][j];
            unsigned xv = 0;
            if (l < 48) xv = xb32[(size_t)sj * 48 + l];
            float x0 = bf2f((unsigned short)(xv & 0xffffu));
            float x1v = bf2f((unsigned short)(xv >> 16));
            float4 wa = *(const float4*)&w_lds[w][j][0];
            float4 wb = *(const float4*)&w_lds[w][j][4];
            float2 wcv = *(const float2*)&w_lds[w][j][8];
            float ww[HEADS] = {wa.x, wa.y, wa.z, wa.w, wb.x, wb.y, wb.z, wb.w, wcv.x, wcv.y};
#pragma unroll
            for (int h = 0; h < HEADS; h++) {
                acc0[h] = fmaf(ww[h], x0, acc0[h]);
                acc1[h] = fmaf(ww[h], x1v, acc1[h]);
            }
        }
        asm volatile("" ::: "memory");
    }

#pragma unroll
    for (int h = 0; h < HEADS; h++)
#pragma unroll
        for (int o = 32; o > 0; o >>= 1) den[h] += __shfl_xor(den[h], o);

    if (l < 48) {
        unsigned* orow = aggb + (size_t)n * 480;
#pragma unroll
        for (int h = 0; h < HEADS; h++) {
            float inv = 1.f / den[h];
            unsigned lo = f2bf(acc0[h] * inv);
            unsigned hi = f2bf(acc1[h] * inv);
            orow[h * 48 + l] = lo | (hi << 16);
        }
    }
}

// ================= GAT layer-2 aggregation + fused graph max-pool ==============
__global__ __launch_bounds__(256) void gat2_agg(
    const int* __restrict__ row_start, const int* __restrict__ csr_src,
    const unsigned short* __restrict__ H2,
    const float* __restrict__ es, const float* __restrict__ ed,
    const float* __restrict__ b, const int* __restrict__ batch,
    unsigned* __restrict__ pk)
{
    const int w = threadIdx.x >> 6, l = threadIdx.x & 63;
    const int n = blockIdx.x * 4 + w;
    const int rs = row_start[n];
    const int deg = row_start[n + 1] - rs;
    const float edv = ed[n];

    float2 acc = {0.f, 0.f};
    float den = 0.f;
    for (int base = 0; base < deg; base += 64) {
        int e = base + l;
        int cnt = min(64, deg - base);
        int s = 0;
        float wv = 0.f;
        if (e < deg) {
            s = csr_src[rs + e];
            float v = es[s] + edv;
            v = (v >= 0.f) ? v : NEG_SLOPE * v;
            wv = __expf(v);
        }
        den += wv;
        for (int j = 0; j < cnt; j++) {
            float wj = __shfl(wv, j);
            int   sj = __shfl(s, j);
            unsigned hp = *(const unsigned*)&H2[(size_t)sj * HID + 2 * l];
            acc.x = fmaf(wj, bf2f((unsigned short)(hp & 0xffffu)), acc.x);
            acc.y = fmaf(wj, bf2f((unsigned short)(hp >> 16)), acc.y);
        }
    }
#pragma unroll
    for (int o = 32; o > 0; o >>= 1) den += __shfl_xor(den, o);

    float inv = 1.f / den;
    float2 bv = *(const float2*)&b[2 * l];
    float v0 = acc.x * inv + bv.x;
    float v1 = acc.y * inv + bv.y;
    v0 = (v0 > 0.f) ? v0 : expm1f(v0);
    v1 = (v1 > 0.f) ? v1 : expm1f(v1);
    int g = batch[n];
    atomicMax(&pk[g * HID + 2 * l], fkey(v0));
    atomicMax(&pk[g * HID + 2 * l + 1], fkey(v1));
}

// ================= decode pooled keys + cell L2-normalize (one kernel) =========
__global__ void decode_cell(const unsigned* __restrict__ pk,
                            unsigned short* __restrict__ pooledb,
                            const float* __restrict__ cell,
                            unsigned short* __restrict__ celln)
{
    int t = threadIdx.x;
    if (blockIdx.x < BGRAPH) {
        int b = blockIdx.x;
        __shared__ float red[256];
        float s = 0.f;
        for (int c = t; c < F_CELL; c += 256) { float v = cell[(size_t)b * F_CELL + c]; s += v * v; }
        red[t] = s; __syncthreads();
        for (int o = 128; o > 0; o >>= 1) { if (t < o) red[t] += red[t + o]; __syncthreads(); }
        float inv = 1.f / fmaxf(sqrtf(red[0]), 1e-12f);
        for (int c = t; c < KPADC; c += 256) {
            float v = (c < F_CELL) ? cell[(size_t)b * F_CELL + c] * inv : 0.f;
            celln[(size_t)b * KPADC + c] = f2bf(v);
        }
    } else {
        int i = (blockIdx.x - BGRAPH) * 256 + t;
        if (i < BGRAPH * HID) pooledb[i] = f2bf(funkey(pk[i]));
    }
}

extern "C" void kernel_launch(void* const* d_in, const int* in_sizes, int n_in,
                              void* d_out, int out_size, void* d_ws, size_t ws_size,
                              hipStream_t stream)
{
    const float* x    = (const float*)d_in[0];
    const int*   ei   = (const int*)d_in[1];
    const int*   batch= (const int*)d_in[2];
    const float* cell = (const float*)d_in[3];
    const float* W1   = (const float*)d_in[4];
    const float* as1  = (const float*)d_in[5];
    const float* ad1  = (const float*)d_in[6];
    const float* b1   = (const float*)d_in[7];
    const float* W2   = (const float*)d_in[8];
    const float* as2  = (const float*)d_in[9];
    const float* ad2  = (const float*)d_in[10];
    const float* b2   = (const float*)d_in[11];
    const float* Wg   = (const float*)d_in[12];
    const float* bg   = (const float*)d_in[13];
    const float* Wf1  = (const float*)d_in[14];
    const float* bf1  = (const float*)d_in[15];
    const float* Wf2  = (const float*)d_in[16];
    const float* bf2  = (const float*)d_in[17];
    const float* Wf3  = (const float*)d_in[18];
    const float* bf3  = (const float*)d_in[19];
    const float* Wo   = (const float*)d_in[20];
    const float* bo   = (const float*)d_in[21];
    float* out = (float*)d_out;

    char* w = (char*)d_ws;
    auto alloc = [&](size_t bytes) { char* p = w; w += (bytes + 255) & ~(size_t)255; return p; };
    unsigned short* xb   = (unsigned short*)alloc((size_t)N_NODES * KPAD1 * 2);   // 3.1 MB
    unsigned short* W1T  = (unsigned short*)alloc((size_t)F1 * KPAD1 * 2);
    unsigned short* F1T  = (unsigned short*)alloc((size_t)32 * KPAD1 * 2);
    unsigned*       aggb = (unsigned*)alloc((size_t)N_NODES * 480 * 4);           // 31.5 MB
    unsigned short* W2T  = (unsigned short*)alloc((size_t)HID * F1 * 2);
    unsigned short* H2   = (unsigned short*)alloc((size_t)N_NODES * HID * 2);     // 4.2 MB
    float*    es1  = (float*)alloc((size_t)N_NODES * HEADS * 4);
    float*    ed1  = (float*)alloc((size_t)N_NODES * HEADS * 4);
    float*    es2  = (float*)alloc((size_t)N_NODES * 4);
    float*    ed2  = (float*)alloc((size_t)N_NODES * 4);
    int*      counts    = (int*)alloc((size_t)N_NODES * 4);
    int*      row_start = (int*)alloc((size_t)(N_NODES + 1) * 4);
    int*      cursor    = (int*)alloc((size_t)N_NODES * 4);
    int*      csr_src   = (int*)alloc((size_t)ETOT * 4);
    unsigned* pk   = (unsigned*)alloc((size_t)BGRAPH * HID * 4);
    unsigned short* pooledb = (unsigned short*)alloc((size_t)BGRAPH * HID * 2);
    unsigned short* WgT  = (unsigned short*)alloc((size_t)HID * HID * 2);
    unsigned short* celln = (unsigned short*)alloc((size_t)BGRAPH * KPADC * 2);
    unsigned short* Wf1T = (unsigned short*)alloc((size_t)2048 * KPADC * 2);
    unsigned short* Wf2T = (unsigned short*)alloc((size_t)512 * 2048 * 2);
    unsigned short* Wf3T = (unsigned short*)alloc((size_t)HID * 512 * 2);
    unsigned short* xc1b = (unsigned short*)alloc((size_t)BGRAPH * 2048 * 2);
    unsigned short* xc2b = (unsigned short*)alloc((size_t)BGRAPH * 512 * 2);

    dim3 b256(256);

    // 0. zero counts (hist runs inside prep_all)
    hipMemsetAsync(counts, 0, (size_t)N_NODES * 4, stream);

    // 1. all prep: converts, transposes, a-fold, zero pk, dst-histogram
    prep_all<<<NB_ELEM + NB_FOLD + NB_ZPK + NB_HIST, b256, 0, stream>>>(
        x, W1, W2, Wf1, Wf2, Wf3, Wg, as1, ad1, ei,
        xb, W1T, W2T, Wf1T, Wf2T, Wf3T, WgT, F1T, counts, pk);

    // 2-3. CSR scan + scatter
    scan_counts<<<1, b256, 0, stream>>>(counts, row_start, cursor);
    scatter_csr<<<(ETOT + 255) / 256, b256, 0, stream>>>(ei, cursor, csr_src);

    // 4. layer-1 coefs: es1/ed1 = x @ folded-a  (db pipeline, 256 blocks)
    gemm_db<2, 1, 2, 0, 0><<<dim3(1, N_NODES / 64), b256, 0, stream>>>(
        xb, F1T, nullptr, nullptr, es1, ed1,
        N_NODES, 32, KPAD1, KPAD1, KPAD1, 32, 0, 0, 0, 0);

    // 5. aggregate raw x per head
    gat1_agg<<<N_NODES / 4, b256, 0, stream>>>(row_start, csr_src, (const unsigned*)xb,
                                               es1, ed1, aggb);

    // 6. H2 = sum_h elu(agg_h @ W1_h + b1_h) @ W2_h  (x1 stays in LDS) + es2/ed2
    w1h2_fused<<<N_NODES / 64, b256, 0, stream>>>(
        (const unsigned short*)aggb, W1T, b1, W2T, H2, as2, ad2, es2, ed2);

    // 7. layer-2 aggregation + fused graph max-pool
    gat2_agg<<<N_NODES / 4, b256, 0, stream>>>(row_start, csr_src, H2, es2, ed2, b2,
                                               batch, pk);

    // 8. decode pooled keys + cell normalize
    decode_cell<<<BGRAPH + (BGRAPH * HID + 255) / 256, b256, 0, stream>>>(
        pk, pooledb, cell, celln);

    // 9. out[:,0:128] = relu(pooled @ Wg + bg)   (direct store, ldc=130)
    mfma_gemm<2, 2, 0, 1, 1><<<dim3(HID / 64, BGRAPH / 64), b256, 0, stream>>>(
        pooledb, WgT, bg, out, nullptr, nullptr,
        BGRAPH, HID, HID, HID, HID, 130);

    // 10-11. cell branch (db pipeline)
    gemm_db<1, 2, 1, 1, 1><<<dim3(2048 / 64, BGRAPH / 32), b256, 0, stream>>>(
        celln, Wf1T, bf1, xc1b, nullptr, nullptr,
        BGRAPH, 2048, KPADC, KPADC, KPADC, 2048, 0, 0, 0, 0);
    gemm_db<1, 2, 1, 1, 1><<<dim3(512 / 64, BGRAPH / 32), b256, 0, stream>>>(
        xc1b, Wf2T, bf2, xc2b, nullptr, nullptr,
        BGRAPH, 512, 2048, 2048, 2048, 512, 0, 0, 0, 0);

    // 12. xc3 = relu(xc2 @ Wf3 + bf3); out[:,128:130] = xc3 @ Wo + bo  (fused)
    mfma_gemm<2, 4, 4, 1, 1><<<dim3(1, BGRAPH / 64), b256, 0, stream>>>(
        xc2b, Wf3T, bf3, out, Wo, bo,
        BGRAPH, HID, 512, 512, 512, 130);
}

// Round 15
// 228.598 us; speedup vs baseline: 1.2120x; 1.2120x over previous
//
#include <hip/hip_runtime.h>
#include <hip/hip_bf16.h>
#include <math.h>

#define N_NODES 16384
#define E_EDGES 131072
#define ETOT (E_EDGES + N_NODES)   // 147456 (self-loops appended)
#define BGRAPH 256
#define F_INPUT 78
#define KPAD1 96                   // F_INPUT padded to mult of 32
#define HID 128
#define HEADS 10
#define F1 (HEADS * HID)           // 1280
#define F_CELL 954
#define KPADC 960                  // F_CELL padded
#define NEG_SLOPE 0.2f

typedef __attribute__((ext_vector_type(8))) short frag_t;   // 8 bf16
typedef __attribute__((ext_vector_type(4))) float f4_t;

static __device__ __forceinline__ unsigned fkey(float f) {
    unsigned b = __float_as_uint(f);
    return (b & 0x80000000u) ? ~b : (b | 0x80000000u);
}
static __device__ __forceinline__ float funkey(unsigned k) {
    unsigned b = (k & 0x80000000u) ? (k ^ 0x80000000u) : ~k;
    return __uint_as_float(b);
}
static __device__ __forceinline__ unsigned short f2bf(float f) {
    __hip_bfloat16 h = __float2bfloat16(f);
    return *(unsigned short*)&h;
}
static __device__ __forceinline__ float bf2f(unsigned short u) {
    return __uint_as_float(((unsigned)u) << 16);
}

// ======== gemm_db: 2-phase double-buffered MFMA GEMM (reg prefetch) ============
// OUT_MODE: 0 = f32 store, 1 = bf16 store,
//           2 = coef1 scatter (cols 0..9 -> esp, 16..25 -> edp)
// ACT: 0 none, 1 relu, 2 elu.
template<int WM16, int WN16, int OUT_MODE, int ACT, int HAS_BIAS>
__global__ __launch_bounds__(256) void gemm_db(
    const unsigned short* __restrict__ A, const unsigned short* __restrict__ BT,
    const float* __restrict__ bias, void* __restrict__ C,
    float* __restrict__ esp, float* __restrict__ edp,
    int M, int N, int K, int lda, int ldb, int ldc,
    int za, int zb, int zc, int zbias)
{
    constexpr int BM = 32 * WM16, BN = 32 * WN16;
    constexpr int LA = BM * 4;
    constexpr int LB = BN * 4;
    constexpr int NA = (LA + 255) / 256;
    constexpr int NB = (LB + 255) / 256;
    __shared__ __align__(16) unsigned short Als[2][BM * 32];
    __shared__ __align__(16) unsigned short Bls[2][BN * 32];
    const int z = blockIdx.z;
    A  += (size_t)z * za;
    BT += (size_t)z * zb;
    const int t = threadIdx.x;
    const int wave = t >> 6, lane = t & 63;
    const int wr = (wave >> 1) * (16 * WM16);
    const int wc = (wave & 1) * (16 * WN16);
    const int row0 = blockIdx.y * BM;
    const int col0 = blockIdx.x * BN;
    const int lrow = lane & 15, kg = lane >> 4;

    uint4 pa[NA], pb[NB];
    auto LOAD = [&](int kk) {
#pragma unroll
        for (int i = 0; i < NA; i++) { int idx = t + i * 256; if (idx < LA) {
            int r = idx >> 2, sl = idx & 3;
            pa[i] = *(const uint4*)&A[(size_t)(row0 + r) * lda + kk + sl * 8]; } }
#pragma unroll
        for (int i = 0; i < NB; i++) { int idx = t + i * 256; if (idx < LB) {
            int r = idx >> 2, sl = idx & 3;
            pb[i] = *(const uint4*)&BT[(size_t)(col0 + r) * ldb + kk + sl * 8]; } }
    };
    auto STORE = [&](int buf) {
#pragma unroll
        for (int i = 0; i < NA; i++) { int idx = t + i * 256; if (idx < LA) {
            int r = idx >> 2, sl = idx & 3;
            *(uint4*)&Als[buf][r * 32 + ((sl ^ (r & 3) ^ ((r >> 2) & 3)) * 8)] = pa[i]; } }
#pragma unroll
        for (int i = 0; i < NB; i++) { int idx = t + i * 256; if (idx < LB) {
            int r = idx >> 2, sl = idx & 3;
            *(uint4*)&Bls[buf][r * 32 + ((sl ^ (r & 3) ^ ((r >> 2) & 3)) * 8)] = pb[i]; } }
    };

    f4_t acc[WM16][WN16];
#pragma unroll
    for (int m = 0; m < WM16; m++)
#pragma unroll
        for (int n = 0; n < WN16; n++) acc[m][n] = (f4_t){0.f, 0.f, 0.f, 0.f};

    LOAD(0);
    STORE(0);
    __syncthreads();

    const int nk = K / 32;
    int cur = 0;
    for (int ks = 0; ks < nk; ks++) {
        if (ks < nk - 1) LOAD((ks + 1) * 32);
        frag_t af[WM16], bfr[WN16];
#pragma unroll
        for (int m = 0; m < WM16; m++) {
            int r = wr + m * 16 + lrow;
            af[m] = *(frag_t*)&Als[cur][r * 32 + ((kg ^ (r & 3) ^ ((r >> 2) & 3)) * 8)];
        }
#pragma unroll
        for (int n = 0; n < WN16; n++) {
            int r = wc + n * 16 + lrow;
            bfr[n] = *(frag_t*)&Bls[cur][r * 32 + ((kg ^ (r & 3) ^ ((r >> 2) & 3)) * 8)];
        }
#pragma unroll
        for (int m = 0; m < WM16; m++)
#pragma unroll
            for (int n = 0; n < WN16; n++)
                acc[m][n] = __builtin_amdgcn_mfma_f32_16x16x32_bf16(af[m], bfr[n], acc[m][n], 0, 0, 0);
        if (ks < nk - 1) STORE(cur ^ 1);
        __syncthreads();
        cur ^= 1;
    }

#pragma unroll
    for (int m = 0; m < WM16; m++) {
#pragma unroll
        for (int n = 0; n < WN16; n++) {
            int col = col0 + wc + n * 16 + lrow;
            float bv = HAS_BIAS ? bias[z * zbias + col] : 0.f;
#pragma unroll
            for (int r = 0; r < 4; r++) {
                int row = row0 + wr + m * 16 + kg * 4 + r;
                float v = acc[m][n][r] + bv;
                if (ACT == 1) v = fmaxf(v, 0.f);
                if (ACT == 2) v = (v > 0.f) ? v : expm1f(v);
                size_t ci = (size_t)row * ldc + (size_t)z * zc + col;
                if (OUT_MODE == 0)      ((float*)C)[ci] = v;
                else if (OUT_MODE == 1) ((unsigned short*)C)[ci] = f2bf(v);
                else {
                    if (col < 10)                  esp[row * 10 + col] = v;
                    else if (col >= 16 && col < 26) edp[row * 10 + (col - 16)] = v;
                }
            }
        }
    }
}

// ================= single-buffered template (small GEMMs: steps 10, 13) ========
// OUT_MODE: 0 = f32 store, 4 = row-reduce with ca=[N][2] -> C[row*ldc+128/129]+cd
template<int WM16, int WN16, int OUT_MODE, int ACT, int HAS_BIAS>
__global__ __launch_bounds__(256) void mfma_gemm(
    const unsigned short* __restrict__ A, const unsigned short* __restrict__ BT,
    const float* __restrict__ bias, void* __restrict__ C,
    const float* __restrict__ ca, const float* __restrict__ cd,
    int M, int N, int Kpad, int lda, int ldb, int ldc)
{
    constexpr int BM = 32 * WM16, BN = 32 * WN16;
    __shared__ __align__(16) unsigned short Als[BM * 32];
    __shared__ __align__(16) unsigned short Bls[BN * 32];
    const int t = threadIdx.x;
    const int wave = t >> 6, lane = t & 63;
    const int wr = (wave >> 1) * (16 * WM16);
    const int wc = (wave & 1) * (16 * WN16);
    const int row0 = blockIdx.y * BM;
    const int col0 = blockIdx.x * BN;

    f4_t acc[WM16][WN16];
#pragma unroll
    for (int m = 0; m < WM16; m++)
#pragma unroll
        for (int n = 0; n < WN16; n++) { acc[m][n] = (f4_t){0.f, 0.f, 0.f, 0.f}; }

    const int lrow = lane & 15, kg = lane >> 4;
    for (int kk = 0; kk < Kpad; kk += 32) {
        for (int i = t; i < BM * 4; i += 256) {
            int r = i >> 2, slot = i & 3;
            uint4 v = *(const uint4*)&A[(size_t)(row0 + r) * lda + kk + slot * 8];
            *(uint4*)&Als[r * 32 + ((slot ^ (r & 3) ^ ((r >> 2) & 3)) * 8)] = v;
        }
        for (int i = t; i < BN * 4; i += 256) {
            int r = i >> 2, slot = i & 3;
            uint4 v = *(const uint4*)&BT[(size_t)(col0 + r) * ldb + kk + slot * 8];
            *(uint4*)&Bls[r * 32 + ((slot ^ (r & 3) ^ ((r >> 2) & 3)) * 8)] = v;
        }
        __syncthreads();
        frag_t af[WM16], bfr[WN16];
#pragma unroll
        for (int m = 0; m < WM16; m++) {
            int r = wr + m * 16 + lrow;
            af[m] = *(frag_t*)&Als[r * 32 + ((kg ^ (r & 3) ^ ((r >> 2) & 3)) * 8)];
        }
#pragma unroll
        for (int n = 0; n < WN16; n++) {
            int r = wc + n * 16 + lrow;
            bfr[n] = *(frag_t*)&Bls[r * 32 + ((kg ^ (r & 3) ^ ((r >> 2) & 3)) * 8)];
        }
#pragma unroll
        for (int m = 0; m < WM16; m++)
#pragma unroll
            for (int n = 0; n < WN16; n++)
                acc[m][n] = __builtin_amdgcn_mfma_f32_16x16x32_bf16(af[m], bfr[n], acc[m][n], 0, 0, 0);
        __syncthreads();
    }

    if constexpr (OUT_MODE == 0) {
#pragma unroll
        for (int m = 0; m < WM16; m++) {
#pragma unroll
            for (int n = 0; n < WN16; n++) {
                int col = col0 + wc + n * 16 + lrow;
                float bv = HAS_BIAS ? bias[col] : 0.f;
#pragma unroll
                for (int r = 0; r < 4; r++) {
                    int row = row0 + wr + m * 16 + kg * 4 + r;
                    float v = acc[m][n][r] + bv;
                    if (ACT == 1) v = fmaxf(v, 0.f);
                    ((float*)C)[(size_t)row * ldc + col] = v;
                }
            }
        }
    } else {
        __shared__ float o2l[BM][2];
        if (t < BM) { o2l[t][0] = 0.f; o2l[t][1] = 0.f; }
        __syncthreads();
#pragma unroll
        for (int m = 0; m < WM16; m++) {
#pragma unroll
            for (int r = 0; r < 4; r++) {
                int lr = wr + m * 16 + kg * 4 + r;
                float p0 = 0.f, p1 = 0.f;
#pragma unroll
                for (int n = 0; n < WN16; n++) {
                    int col = col0 + wc + n * 16 + lrow;
                    float v = acc[m][n][r] + (HAS_BIAS ? bias[col] : 0.f);
                    if (ACT == 1) v = fmaxf(v, 0.f);
                    p0 = fmaf(v, ca[col * 2], p0);
                    p1 = fmaf(v, ca[col * 2 + 1], p1);
                }
                atomicAdd(&o2l[lr][0], p0);
                atomicAdd(&o2l[lr][1], p1);
            }
        }
        __syncthreads();
        if (t < BM) {
            ((float*)C)[(size_t)(row0 + t) * ldc + 128] = o2l[t][0] + cd[0];
            ((float*)C)[(size_t)(row0 + t) * ldc + 129] = o2l[t][1] + cd[1];
        }
    }
}

// ================= w1_apply: x1[:,h*128:(h+1)*128] = elu(agg_h @ W1h + b1h) ====
// K=96 staged entirely in LDS (no K-loop barriers); LDS-staged wide-store
// epilogue kills the 2x HBM write amplification of scattered bf16 stores.
// grid (N/128, HEADS), 256 threads.
__global__ __launch_bounds__(256) void w1_apply(
    const unsigned short* __restrict__ aggb,   // [N,960] bf16, head h at cols h*96
    const unsigned short* __restrict__ W1T,    // [1280,96] bf16
    const float* __restrict__ b1,              // [1280]
    unsigned short* __restrict__ x1)           // [N,1280] bf16
{
    __shared__ __align__(16) unsigned short ls[24576];   // A:[0,12288) B:[12288,24576)
    const int z = blockIdx.y;
    const int row0 = blockIdx.x * 128;
    const int t = threadIdx.x;
    const int wave = t >> 6, lane = t & 63;
    const int wr = (wave >> 1) * 64;
    const int wc = (wave & 1) * 64;
    const int lrow = lane & 15, kg = lane >> 4;

    const unsigned short* A = aggb + (size_t)z * 96;            // lda = 960
    const unsigned short* B = W1T + (size_t)z * 128 * 96;       // ldb = 96

    // stage full A[128,96] and B[128,96] tiles (12 uint4/thread)
    for (int i = t; i < 1536; i += 256) {
        int r = i / 12, c = i % 12;
        int ks = c >> 2, sl = c & 3;
        int swz = ((sl ^ (r & 3) ^ ((r >> 2) & 3)) * 8);
        uint4 va = *(const uint4*)&A[(size_t)(row0 + r) * 960 + ks * 32 + sl * 8];
        *(uint4*)&ls[(ks * 128 + r) * 32 + swz] = va;
        uint4 vb = *(const uint4*)&B[(size_t)r * 96 + ks * 32 + sl * 8];
        *(uint4*)&ls[12288 + (ks * 128 + r) * 32 + swz] = vb;
    }
    __syncthreads();

    f4_t acc[4][4];
#pragma unroll
    for (int m = 0; m < 4; m++)
#pragma unroll
        for (int n = 0; n < 4; n++) acc[m][n] = (f4_t){0.f, 0.f, 0.f, 0.f};

#pragma unroll
    for (int ks = 0; ks < 3; ks++) {
        frag_t af[4], bfr[4];
#pragma unroll
        for (int m = 0; m < 4; m++) {
            int r = wr + m * 16 + lrow;
            af[m] = *(frag_t*)&ls[(ks * 128 + r) * 32 + ((kg ^ (r & 3) ^ ((r >> 2) & 3)) * 8)];
        }
#pragma unroll
        for (int n = 0; n < 4; n++) {
            int r = wc + n * 16 + lrow;
            bfr[n] = *(frag_t*)&ls[12288 + (ks * 128 + r) * 32 + ((kg ^ (r & 3) ^ ((r >> 2) & 3)) * 8)];
        }
#pragma unroll
        for (int m = 0; m < 4; m++)
#pragma unroll
            for (int n = 0; n < 4; n++)
                acc[m][n] = __builtin_amdgcn_mfma_f32_16x16x32_bf16(af[m], bfr[n], acc[m][n], 0, 0, 0);
    }
    __syncthreads();   // all frag reads done; ls reusable

    // bias + elu, stage bf16 tile [128][128] into ls
#pragma unroll
    for (int m = 0; m < 4; m++) {
#pragma unroll
        for (int n = 0; n < 4; n++) {
            int col = wc + n * 16 + lrow;
            float bv = b1[z * HID + col];
#pragma unroll
            for (int r = 0; r < 4; r++) {
                int lr = wr + m * 16 + kg * 4 + r;
                float v = acc[m][n][r] + bv;
                v = (v > 0.f) ? v : expm1f(v);
                ls[lr * 128 + col] = f2bf(v);
            }
        }
    }
    __syncthreads();

    // wide store: 128 rows x 256 B contiguous (2048 uint4)
    for (int i = t; i < 2048; i += 256) {
        int r = i >> 4, seg = i & 15;
        *(uint4*)&x1[(size_t)(row0 + r) * F1 + z * HID + seg * 8] =
            *(const uint4*)&ls[r * 128 + seg * 8];
    }
}

// ================= H2 GEMM: double-buffered + fused es2/ed2 + wide store =======
__global__ __launch_bounds__(256) void h2_gemm(
    const unsigned short* __restrict__ A, const unsigned short* __restrict__ BT,
    unsigned short* __restrict__ C,
    const float* __restrict__ as2, const float* __restrict__ ad2,
    float* __restrict__ es2, float* __restrict__ ed2)
{
    __shared__ __align__(16) unsigned short Als[2][32 * 32];
    __shared__ __align__(16) unsigned short Bls[2][128 * 32];
    __shared__ __align__(16) unsigned short ob[32 * 128];
    __shared__ float esl[4][32], edl[4][32];
    const int t = threadIdx.x;
    const int wave = t >> 6, lane = t & 63;
    const int lrow = lane & 15, kg = lane >> 4;
    const int row0 = blockIdx.x * 32;
    const int wc = wave * 32;

    const int ar = t >> 2, asl = t & 3;
    const int br = t >> 2, bsl = t & 3;

    uint4 pa, pb0, pb1;
    auto LOAD = [&](int kk) {
        if (t < 128) pa = *(const uint4*)&A[(size_t)(row0 + ar) * F1 + kk + asl * 8];
        pb0 = *(const uint4*)&BT[(size_t)br * F1 + kk + bsl * 8];
        pb1 = *(const uint4*)&BT[(size_t)(br + 64) * F1 + kk + bsl * 8];
    };
    auto STORE = [&](int buf) {
        if (t < 128)
            *(uint4*)&Als[buf][ar * 32 + ((asl ^ (ar & 3) ^ ((ar >> 2) & 3)) * 8)] = pa;
        *(uint4*)&Bls[buf][br * 32 + ((bsl ^ (br & 3) ^ ((br >> 2) & 3)) * 8)] = pb0;
        int r2 = br + 64;
        *(uint4*)&Bls[buf][r2 * 32 + ((bsl ^ (r2 & 3) ^ ((r2 >> 2) & 3)) * 8)] = pb1;
    };

    LOAD(0);
    STORE(0);
    __syncthreads();

    f4_t acc[2][2];
#pragma unroll
    for (int m = 0; m < 2; m++)
#pragma unroll
        for (int n = 0; n < 2; n++) acc[m][n] = (f4_t){0.f, 0.f, 0.f, 0.f};

    int cur = 0;
    for (int ks = 0; ks < 40; ks++) {
        if (ks < 39) LOAD((ks + 1) * 32);
        frag_t af[2], bfr[2];
#pragma unroll
        for (int m = 0; m < 2; m++) {
            int r = m * 16 + lrow;
            af[m] = *(frag_t*)&Als[cur][r * 32 + ((kg ^ (r & 3) ^ ((r >> 2) & 3)) * 8)];
        }
#pragma unroll
        for (int n = 0; n < 2; n++) {
            int r = wc + n * 16 + lrow;
            bfr[n] = *(frag_t*)&Bls[cur][r * 32 + ((kg ^ (r & 3) ^ ((r >> 2) & 3)) * 8)];
        }
#pragma unroll
        for (int m = 0; m < 2; m++)
#pragma unroll
            for (int n = 0; n < 2; n++)
                acc[m][n] = __builtin_amdgcn_mfma_f32_16x16x32_bf16(af[m], bfr[n], acc[m][n], 0, 0, 0);
        if (ks < 39) STORE(cur ^ 1);
        __syncthreads();
        cur ^= 1;
    }

    // stage bf16 + per-row dot with as2/ad2
#pragma unroll
    for (int m = 0; m < 2; m++) {
#pragma unroll
        for (int r = 0; r < 4; r++) {
            int lr = m * 16 + kg * 4 + r;
            float pes = 0.f, ped = 0.f;
#pragma unroll
            for (int n = 0; n < 2; n++) {
                int col = wc + n * 16 + lrow;
                float v = acc[m][n][r];
                ob[lr * 128 + col] = f2bf(v);
                pes = fmaf(v, as2[col], pes);
                ped = fmaf(v, ad2[col], ped);
            }
#pragma unroll
            for (int o = 1; o < 16; o <<= 1) {
                pes += __shfl_xor(pes, o);
                ped += __shfl_xor(ped, o);
            }
            if (lrow == 0) { esl[wave][lr] = pes; edl[wave][lr] = ped; }
        }
    }
    __syncthreads();
    // wide store: 32 rows x 256 B (512 uint4)
    for (int i = t; i < 512; i += 256) {
        int r = i >> 4, seg = i & 15;
        *(uint4*)&C[(size_t)(row0 + r) * HID + seg * 8] = *(const uint4*)&ob[r * 128 + seg * 8];
    }
    if (t < 32) {
        es2[row0 + t] = esl[0][t] + esl[1][t] + esl[2][t] + esl[3][t];
        ed2[row0 + t] = edl[0][t] + edl[1][t] + edl[2][t] + edl[3][t];
    }
}

// ================= mega prep: converts + transposes + fold + zero-pk + hist ====
#define S0 1572864   // xb: 16384*96
#define S1 122880    // W1T: 1280*96
#define S2 163840    // W2T: 128*1280
#define S3 1966080   // Wf1T: 2048*960
#define S4 1048576   // Wf2T: 512*2048
#define S5 65536     // Wf3T: 128*512
#define S6 16384     // WgT: 128*128
#define PREP_TOTAL (S0+S1+S2+S3+S4+S5+S6)   // 4956160 = 19360*256
#define NB_ELEM (PREP_TOTAL / 256)          // 19360
#define NB_FOLD 768                          // 3072 fold entries, 4 waves/block
#define NB_ZPK  128                          // pk: 32768
#define NB_HIST ((ETOT + 255) / 256)         // 576

__global__ void prep_all(const float* __restrict__ x,  const float* __restrict__ W1,
                         const float* __restrict__ W2, const float* __restrict__ Wf1,
                         const float* __restrict__ Wf2, const float* __restrict__ Wf3,
                         const float* __restrict__ Wg,
                         const float* __restrict__ as1, const float* __restrict__ ad1,
                         const int* __restrict__ ei,
                         unsigned short* __restrict__ xb,  unsigned short* __restrict__ W1T,
                         unsigned short* __restrict__ W2T, unsigned short* __restrict__ Wf1T,
                         unsigned short* __restrict__ Wf2T, unsigned short* __restrict__ Wf3T,
                         unsigned short* __restrict__ WgT, unsigned short* __restrict__ F1T,
                         int* __restrict__ counts, unsigned* __restrict__ pk)
{
    int blk = blockIdx.x, t = threadIdx.x;
    if (blk < NB_ELEM) {
        int i = blk * 256 + t;
        if (i < S0) { int r = i / 96, k = i % 96;
            xb[i] = (k < F_INPUT) ? f2bf(x[r * F_INPUT + k]) : 0; return; }
        i -= S0;
        if (i < S1) { int n = i / 96, k = i % 96;
            W1T[i] = (k < F_INPUT) ? f2bf(W1[(size_t)k * F1 + n]) : 0; return; }
        i -= S1;
        if (i < S2) { int n = i / 1280, k = i % 1280;
            W2T[i] = f2bf(W2[(size_t)k * HID + n]); return; }
        i -= S2;
        if (i < S3) { int n = i / 960, k = i % 960;
            Wf1T[i] = (k < F_CELL) ? f2bf(Wf1[(size_t)k * 2048 + n]) : 0; return; }
        i -= S3;
        if (i < S4) { int n = i / 2048, k = i % 2048;
            Wf2T[i] = f2bf(Wf2[(size_t)k * 512 + n]); return; }
        i -= S4;
        if (i < S5) { int n = i / 512, k = i % 512;
            Wf3T[i] = f2bf(Wf3[(size_t)k * HID + n]); return; }
        i -= S5;
        { int n = i / 128, k = i % 128;
            WgT[i] = f2bf(Wg[(size_t)k * HID + n]); }
        return;
    }
    blk -= NB_ELEM;
    if (blk < NB_FOLD) {
        int idx = blk * 4 + (t >> 6);
        int l = t & 63;
        int r = idx / 96, k = idx % 96;
        int sd = r >> 4, h = r & 15;
        float p = 0.f;
        if (h < HEADS && k < F_INPUT) {
            const float* a = (sd ? ad1 : as1) + h * HID;
            float2 wv = *(const float2*)&W1[(size_t)k * F1 + h * HID + 2 * l];
            float2 av = *(const float2*)&a[2 * l];
            p = wv.x * av.x + wv.y * av.y;
#pragma unroll
            for (int o = 32; o > 0; o >>= 1) p += __shfl_xor(p, o);
        }
        if (l == 0) F1T[(size_t)r * 96 + k] = f2bf(p);
        return;
    }
    blk -= NB_FOLD;
    if (blk < NB_ZPK) { pk[blk * 256 + t] = 0; return; }   // 0 < fkey(any float)
    blk -= NB_ZPK;
    int e = blk * 256 + t;
    if (e < ETOT) {
        int dst = (e < E_EDGES) ? ei[E_EDGES + e] : (e - E_EDGES);
        atomicAdd(&counts[dst], 1);
    }
}

// ================= CSR scan (vectorized) + scatter =================
__global__ void scan_counts(const int* __restrict__ counts,
                            int* __restrict__ row_start, int* __restrict__ cursor)
{
    __shared__ int part[256];
    int t = threadIdx.x;
    int base = t * 64;
    int4 v[16];
#pragma unroll
    for (int i = 0; i < 16; i++) v[i] = *(const int4*)&counts[base + i * 4];
    int sum = 0;
#pragma unroll
    for (int i = 0; i < 16; i++) sum += v[i].x + v[i].y + v[i].z + v[i].w;
    part[t] = sum;
    __syncthreads();
    for (int o = 1; o < 256; o <<= 1) {
        int vv = (t >= o) ? part[t - o] : 0;
        __syncthreads();
        part[t] += vv;
        __syncthreads();
    }
    int run = (t == 0) ? 0 : part[t - 1];
#pragma unroll
    for (int i = 0; i < 16; i++) {
        int4 w;
        w.x = run; run += v[i].x;
        w.y = run; run += v[i].y;
        w.z = run; run += v[i].z;
        w.w = run; run += v[i].w;
        *(int4*)&row_start[base + i * 4] = w;
        *(int4*)&cursor[base + i * 4] = w;
    }
    if (t == 255) row_start[N_NODES] = run;
}

__global__ void scatter_csr(const int* __restrict__ ei, int* __restrict__ cursor,
                            int* __restrict__ csr_src)
{
    int e = blockIdx.x * blockDim.x + threadIdx.x;
    if (e >= ETOT) return;
    int src, dst;
    if (e < E_EDGES) { src = ei[e]; dst = ei[E_EDGES + e]; } else { src = dst = e - E_EDGES; }
    int pos = atomicAdd(&cursor[dst], 1);
    csr_src[pos] = src;
}

// ================= GAT layer-1 aggregation over RAW x (96 bf16 per row) ========
__global__ __launch_bounds__(256) void gat1_agg(
    const int* __restrict__ row_start, const int* __restrict__ csr_src,
    const unsigned* __restrict__ xb32,          // [N,48] u32 = 96 bf16
    const float* __restrict__ es, const float* __restrict__ ed,
    unsigned* __restrict__ aggb)                // [N,480] u32 = 960 bf16
{
    const int w = threadIdx.x >> 6, l = threadIdx.x & 63;
    const int n = blockIdx.x * 4 + w;
    const int rs = row_start[n];
    const int deg = row_start[n + 1] - rs;

    __shared__ __align__(16) float w_lds[4][64][12];
    __shared__ int src_lds[4][64];

    float edv[HEADS];
    const float* edp = ed + n * HEADS;
#pragma unroll
    for (int h = 0; h < HEADS; h++) edv[h] = edp[h];

    float acc0[HEADS], acc1[HEADS], den[HEADS];
#pragma unroll
    for (int h = 0; h < HEADS; h++) { acc0[h] = 0.f; acc1[h] = 0.f; den[h] = 0.f; }

    for (int base = 0; base < deg; base += 64) {
        int e = base + l;
        int cnt = min(64, deg - base);
        float wv[HEADS];
        if (e < deg) {
            int s = csr_src[rs + e];
            src_lds[w][l] = s;
            const float* ep = es + s * HEADS;
#pragma unroll
            for (int h = 0; h < HEADS; h++) {
                float v = ep[h] + edv[h];
                v = (v >= 0.f) ? v : NEG_SLOPE * v;
                wv[h] = __expf(v);
            }
        } else {
#pragma unroll
            for (int h = 0; h < HEADS; h++) wv[h] = 0.f;
        }
#pragma unroll
        for (int h = 0; h < HEADS; h++) {
            den[h] += wv[h];
            w_lds[w][l][h] = wv[h];
        }
        asm volatile("" ::: "memory");

        for (int j = 0; j < cnt; j++) {
            int sj = src_lds[w][j];
            unsigned xv = 0;
            if (l < 48) xv = xb32[(size_t)sj * 48 + l];
            float x0 = bf2f((unsigned short)(xv & 0xffffu));
            float x1v = bf2f((unsigned short)(xv >> 16));
            float4 wa = *(const float4*)&w_lds[w][j][0];
            float4 wb = *(const float4*)&w_lds[w][j][4];
            float2 wcv = *(const float2*)&w_lds[w][j][8];
            float ww[HEADS] = {wa.x, wa.y, wa.z, wa.w, wb.x, wb.y, wb.z, wb.w, wcv.x, wcv.y};
#pragma unroll
            for (int h = 0; h < HEADS; h++) {
                acc0[h] = fmaf(ww[h], x0, acc0[h]);
                acc1[h] = fmaf(ww[h], x1v, acc1[h]);
            }
        }
        asm volatile("" ::: "memory");
    }

#pragma unroll
    for (int h = 0; h < HEADS; h++)
#pragma unroll
        for (int o = 32; o > 0; o >>= 1) den[h] += __shfl_xor(den[h], o);

    if (l < 48) {
        unsigned* orow = aggb + (size_t)n * 480;
#pragma unroll
        for (int h = 0; h < HEADS; h++) {
            float inv = 1.f / den[h];
            unsigned lo = f2bf(acc0[h] * inv);
            unsigned hi = f2bf(acc1[h] * inv);
            orow[h * 48 + l] = lo | (hi << 16);
        }
    }
}

// ================= GAT layer-2 aggregation + fused graph max-pool ==============
__global__ __launch_bounds__(256) void gat2_agg(
    const int* __restrict__ row_start, const int* __restrict__ csr_src,
    const unsigned short* __restrict__ H2,
    const float* __restrict__ es, const float* __restrict__ ed,
    const float* __restrict__ b, const int* __restrict__ batch,
    unsigned* __restrict__ pk)
{
    const int w = threadIdx.x >> 6, l = threadIdx.x & 63;
    const int n = blockIdx.x * 4 + w;
    const int rs = row_start[n];
    const int deg = row_start[n + 1] - rs;
    const float edv = ed[n];

    float2 acc = {0.f, 0.f};
    float den = 0.f;
    for (int base = 0; base < deg; base += 64) {
        int e = base + l;
        int cnt = min(64, deg - base);
        int s = 0;
        float wv = 0.f;
        if (e < deg) {
            s = csr_src[rs + e];
            float v = es[s] + edv;
            v = (v >= 0.f) ? v : NEG_SLOPE * v;
            wv = __expf(v);
        }
        den += wv;
        for (int j = 0; j < cnt; j++) {
            float wj = __shfl(wv, j);
            int   sj = __shfl(s, j);
            unsigned hp = *(const unsigned*)&H2[(size_t)sj * HID + 2 * l];
            acc.x = fmaf(wj, bf2f((unsigned short)(hp & 0xffffu)), acc.x);
            acc.y = fmaf(wj, bf2f((unsigned short)(hp >> 16)), acc.y);
        }
    }
#pragma unroll
    for (int o = 32; o > 0; o >>= 1) den += __shfl_xor(den, o);

    float inv = 1.f / den;
    float2 bv = *(const float2*)&b[2 * l];
    float v0 = acc.x * inv + bv.x;
    float v1 = acc.y * inv + bv.y;
    v0 = (v0 > 0.f) ? v0 : expm1f(v0);
    v1 = (v1 > 0.f) ? v1 : expm1f(v1);
    int g = batch[n];
    atomicMax(&pk[g * HID + 2 * l], fkey(v0));
    atomicMax(&pk[g * HID + 2 * l + 1], fkey(v1));
}

// ================= decode pooled keys + cell L2-normalize (one kernel) =========
__global__ void decode_cell(const unsigned* __restrict__ pk,
                            unsigned short* __restrict__ pooledb,
                            const float* __restrict__ cell,
                            unsigned short* __restrict__ celln)
{
    int t = threadIdx.x;
    if (blockIdx.x < BGRAPH) {
        int b = blockIdx.x;
        __shared__ float red[256];
        float s = 0.f;
        for (int c = t; c < F_CELL; c += 256) { float v = cell[(size_t)b * F_CELL + c]; s += v * v; }
        red[t] = s; __syncthreads();
        for (int o = 128; o > 0; o >>= 1) { if (t < o) red[t] += red[t + o]; __syncthreads(); }
        float inv = 1.f / fmaxf(sqrtf(red[0]), 1e-12f);
        for (int c = t; c < KPADC; c += 256) {
            float v = (c < F_CELL) ? cell[(size_t)b * F_CELL + c] * inv : 0.f;
            celln[(size_t)b * KPADC + c] = f2bf(v);
        }
    } else {
        int i = (blockIdx.x - BGRAPH) * 256 + t;
        if (i < BGRAPH * HID) pooledb[i] = f2bf(funkey(pk[i]));
    }
}

extern "C" void kernel_launch(void* const* d_in, const int* in_sizes, int n_in,
                              void* d_out, int out_size, void* d_ws, size_t ws_size,
                              hipStream_t stream)
{
    const float* x    = (const float*)d_in[0];
    const int*   ei   = (const int*)d_in[1];
    const int*   batch= (const int*)d_in[2];
    const float* cell = (const float*)d_in[3];
    const float* W1   = (const float*)d_in[4];
    const float* as1  = (const float*)d_in[5];
    const float* ad1  = (const float*)d_in[6];
    const float* b1   = (const float*)d_in[7];
    const float* W2   = (const float*)d_in[8];
    const float* as2  = (const float*)d_in[9];
    const float* ad2  = (const float*)d_in[10];
    const float* b2   = (const float*)d_in[11];
    const float* Wg   = (const float*)d_in[12];
    const float* bg   = (const float*)d_in[13];
    const float* Wf1  = (const float*)d_in[14];
    const float* bf1  = (const float*)d_in[15];
    const float* Wf2  = (const float*)d_in[16];
    const float* bf2  = (const float*)d_in[17];
    const float* Wf3  = (const float*)d_in[18];
    const float* bf3  = (const float*)d_in[19];
    const float* Wo   = (const float*)d_in[20];
    const float* bo   = (const float*)d_in[21];
    float* out = (float*)d_out;

    char* w = (char*)d_ws;
    auto alloc = [&](size_t bytes) { char* p = w; w += (bytes + 255) & ~(size_t)255; return p; };
    unsigned short* xb   = (unsigned short*)alloc((size_t)N_NODES * KPAD1 * 2);   // 3.1 MB
    unsigned short* W1T  = (unsigned short*)alloc((size_t)F1 * KPAD1 * 2);
    unsigned short* F1T  = (unsigned short*)alloc((size_t)32 * KPAD1 * 2);
    unsigned*       aggb = (unsigned*)alloc((size_t)N_NODES * 480 * 4);           // 31.5 MB
    unsigned short* x1   = (unsigned short*)alloc((size_t)N_NODES * F1 * 2);      // 42 MB
    unsigned short* W2T  = (unsigned short*)alloc((size_t)HID * F1 * 2);
    unsigned short* H2   = (unsigned short*)alloc((size_t)N_NODES * HID * 2);     // 4.2 MB
    float*    es1  = (float*)alloc((size_t)N_NODES * HEADS * 4);
    float*    ed1  = (float*)alloc((size_t)N_NODES * HEADS * 4);
    float*    es2  = (float*)alloc((size_t)N_NODES * 4);
    float*    ed2  = (float*)alloc((size_t)N_NODES * 4);
    int*      counts    = (int*)alloc((size_t)N_NODES * 4);
    int*      row_start = (int*)alloc((size_t)(N_NODES + 1) * 4);
    int*      cursor    = (int*)alloc((size_t)N_NODES * 4);
    int*      csr_src   = (int*)alloc((size_t)ETOT * 4);
    unsigned* pk   = (unsigned*)alloc((size_t)BGRAPH * HID * 4);
    unsigned short* pooledb = (unsigned short*)alloc((size_t)BGRAPH * HID * 2);
    unsigned short* WgT  = (unsigned short*)alloc((size_t)HID * HID * 2);
    unsigned short* celln = (unsigned short*)alloc((size_t)BGRAPH * KPADC * 2);
    unsigned short* Wf1T = (unsigned short*)alloc((size_t)2048 * KPADC * 2);
    unsigned short* Wf2T = (unsigned short*)alloc((size_t)512 * 2048 * 2);
    unsigned short* Wf3T = (unsigned short*)alloc((size_t)HID * 512 * 2);
    unsigned short* xc1b = (unsigned short*)alloc((size_t)BGRAPH * 2048 * 2);
    unsigned short* xc2b = (unsigned short*)alloc((size_t)BGRAPH * 512 * 2);

    dim3 b256(256);

    // 0. zero counts (hist runs inside prep_all)
    hipMemsetAsync(counts, 0, (size_t)N_NODES * 4, stream);

    // 1. all prep: converts, transposes, a-fold, zero pk, dst-histogram
    prep_all<<<NB_ELEM + NB_FOLD + NB_ZPK + NB_HIST, b256, 0, stream>>>(
        x, W1, W2, Wf1, Wf2, Wf3, Wg, as1, ad1, ei,
        xb, W1T, W2T, Wf1T, Wf2T, Wf3T, WgT, F1T, counts, pk);

    // 2-3. CSR scan + scatter
    scan_counts<<<1, b256, 0, stream>>>(counts, row_start, cursor);
    scatter_csr<<<(ETOT + 255) / 256, b256, 0, stream>>>(ei, cursor, csr_src);

    // 4. layer-1 coefs: es1/ed1 = x @ folded-a  (db pipeline, 256 blocks)
    gemm_db<2, 1, 2, 0, 0><<<dim3(1, N_NODES / 64), b256, 0, stream>>>(
        xb, F1T, nullptr, nullptr, es1, ed1,
        N_NODES, 32, KPAD1, KPAD1, KPAD1, 32, 0, 0, 0, 0);

    // 5. aggregate raw x per head
    gat1_agg<<<N_NODES / 4, b256, 0, stream>>>(row_start, csr_src, (const unsigned*)xb,
                                               es1, ed1, aggb);

    // 6. x1 = elu(agg @ W1 + b1), per head; LDS-wide stores (no write amp)
    w1_apply<<<dim3(N_NODES / 128, HEADS), b256, 0, stream>>>(
        (const unsigned short*)aggb, W1T, b1, x1);

    // 7. H2 = x1 @ W2 (db pipeline) + fused es2/ed2 + wide store
    h2_gemm<<<N_NODES / 32, b256, 0, stream>>>(x1, W2T, H2, as2, ad2, es2, ed2);

    // 8. layer-2 aggregation + fused graph max-pool
    gat2_agg<<<N_NODES / 4, b256, 0, stream>>>(row_start, csr_src, H2, es2, ed2, b2,
                                               batch, pk);

    // 9. decode pooled keys + cell normalize
    decode_cell<<<BGRAPH + (BGRAPH * HID + 255) / 256, b256, 0, stream>>>(
        pk, pooledb, cell, celln);

    // 10. out[:,0:128] = relu(pooled @ Wg + bg)   (direct store, ldc=130)
    mfma_gemm<2, 2, 0, 1, 1><<<dim3(HID / 64, BGRAPH / 64), b256, 0, stream>>>(
        pooledb, WgT, bg, out, nullptr, nullptr,
        BGRAPH, HID, HID, HID, HID, 130);

    // 11-12. cell branch (db pipeline)
    gemm_db<1, 2, 1, 1, 1><<<dim3(2048 / 64, BGRAPH / 32), b256, 0, stream>>>(
        celln, Wf1T, bf1, xc1b, nullptr, nullptr,
        BGRAPH, 2048, KPADC, KPADC, KPADC, 2048, 0, 0, 0, 0);
    gemm_db<1, 2, 1, 1, 1><<<dim3(512 / 64, BGRAPH / 32), b256, 0, stream>>>(
        xc1b, Wf2T, bf2, xc2b, nullptr, nullptr,
        BGRAPH, 512, 2048, 2048, 2048, 512, 0, 0, 0, 0);

    // 13. xc3 = relu(xc2 @ Wf3 + bf3); out[:,128:130] = xc3 @ Wo + bo  (fused)
    mfma_gemm<2, 4, 4, 1, 1><<<dim3(1, BGRAPH / 64), b256, 0, stream>>>(
        xc2b, Wf3T, bf3, out, Wo, bo,
        BGRAPH, HID, 512, 512, 512, 130);
}

// Round 16
// 225.420 us; speedup vs baseline: 1.2291x; 1.0141x over previous
//
#include <hip/hip_runtime.h>
#include <hip/hip_bf16.h>
#include <math.h>

#define N_NODES 16384
#define E_EDGES 131072
#define ETOT (E_EDGES + N_NODES)   // 147456 (self-loops appended)
#define BGRAPH 256
#define F_INPUT 78
#define KPAD1 96                   // F_INPUT padded to mult of 32
#define HID 128
#define HEADS 10
#define F1 (HEADS * HID)           // 1280
#define F_CELL 954
#define KPADC 960                  // F_CELL padded
#define NEG_SLOPE 0.2f

typedef __attribute__((ext_vector_type(8))) short frag_t;   // 8 bf16
typedef __attribute__((ext_vector_type(4))) float f4_t;

static __device__ __forceinline__ unsigned fkey(float f) {
    unsigned b = __float_as_uint(f);
    return (b & 0x80000000u) ? ~b : (b | 0x80000000u);
}
static __device__ __forceinline__ float funkey(unsigned k) {
    unsigned b = (k & 0x80000000u) ? (k ^ 0x80000000u) : ~k;
    return __uint_as_float(b);
}
static __device__ __forceinline__ unsigned short f2bf(float f) {
    __hip_bfloat16 h = __float2bfloat16(f);
    return *(unsigned short*)&h;
}
static __device__ __forceinline__ float bf2f(unsigned short u) {
    return __uint_as_float(((unsigned)u) << 16);
}

// ======== gemm_db: 2-phase double-buffered MFMA GEMM (reg prefetch) ============
// OUT_MODE: 0 = f32 store, 1 = bf16 store,
//           2 = coef1 scatter (cols 0..9 -> esp, 16..25 -> edp)
// ACT: 0 none, 1 relu, 2 elu.
template<int WM16, int WN16, int OUT_MODE, int ACT, int HAS_BIAS>
__global__ __launch_bounds__(256) void gemm_db(
    const unsigned short* __restrict__ A, const unsigned short* __restrict__ BT,
    const float* __restrict__ bias, void* __restrict__ C,
    float* __restrict__ esp, float* __restrict__ edp,
    int M, int N, int K, int lda, int ldb, int ldc,
    int za, int zb, int zc, int zbias)
{
    constexpr int BM = 32 * WM16, BN = 32 * WN16;
    constexpr int LA = BM * 4;
    constexpr int LB = BN * 4;
    constexpr int NA = (LA + 255) / 256;
    constexpr int NB = (LB + 255) / 256;
    __shared__ __align__(16) unsigned short Als[2][BM * 32];
    __shared__ __align__(16) unsigned short Bls[2][BN * 32];
    const int z = blockIdx.z;
    A  += (size_t)z * za;
    BT += (size_t)z * zb;
    const int t = threadIdx.x;
    const int wave = t >> 6, lane = t & 63;
    const int wr = (wave >> 1) * (16 * WM16);
    const int wc = (wave & 1) * (16 * WN16);
    const int row0 = blockIdx.y * BM;
    const int col0 = blockIdx.x * BN;
    const int lrow = lane & 15, kg = lane >> 4;

    uint4 pa[NA], pb[NB];
    auto LOAD = [&](int kk) {
#pragma unroll
        for (int i = 0; i < NA; i++) { int idx = t + i * 256; if (idx < LA) {
            int r = idx >> 2, sl = idx & 3;
            pa[i] = *(const uint4*)&A[(size_t)(row0 + r) * lda + kk + sl * 8]; } }
#pragma unroll
        for (int i = 0; i < NB; i++) { int idx = t + i * 256; if (idx < LB) {
            int r = idx >> 2, sl = idx & 3;
            pb[i] = *(const uint4*)&BT[(size_t)(col0 + r) * ldb + kk + sl * 8]; } }
    };
    auto STORE = [&](int buf) {
#pragma unroll
        for (int i = 0; i < NA; i++) { int idx = t + i * 256; if (idx < LA) {
            int r = idx >> 2, sl = idx & 3;
            *(uint4*)&Als[buf][r * 32 + ((sl ^ (r & 3) ^ ((r >> 2) & 3)) * 8)] = pa[i]; } }
#pragma unroll
        for (int i = 0; i < NB; i++) { int idx = t + i * 256; if (idx < LB) {
            int r = idx >> 2, sl = idx & 3;
            *(uint4*)&Bls[buf][r * 32 + ((sl ^ (r & 3) ^ ((r >> 2) & 3)) * 8)] = pb[i]; } }
    };

    f4_t acc[WM16][WN16];
#pragma unroll
    for (int m = 0; m < WM16; m++)
#pragma unroll
        for (int n = 0; n < WN16; n++) acc[m][n] = (f4_t){0.f, 0.f, 0.f, 0.f};

    LOAD(0);
    STORE(0);
    __syncthreads();

    const int nk = K / 32;
    int cur = 0;
    for (int ks = 0; ks < nk; ks++) {
        if (ks < nk - 1) LOAD((ks + 1) * 32);
        frag_t af[WM16], bfr[WN16];
#pragma unroll
        for (int m = 0; m < WM16; m++) {
            int r = wr + m * 16 + lrow;
            af[m] = *(frag_t*)&Als[cur][r * 32 + ((kg ^ (r & 3) ^ ((r >> 2) & 3)) * 8)];
        }
#pragma unroll
        for (int n = 0; n < WN16; n++) {
            int r = wc + n * 16 + lrow;
            bfr[n] = *(frag_t*)&Bls[cur][r * 32 + ((kg ^ (r & 3) ^ ((r >> 2) & 3)) * 8)];
        }
#pragma unroll
        for (int m = 0; m < WM16; m++)
#pragma unroll
            for (int n = 0; n < WN16; n++)
                acc[m][n] = __builtin_amdgcn_mfma_f32_16x16x32_bf16(af[m], bfr[n], acc[m][n], 0, 0, 0);
        if (ks < nk - 1) STORE(cur ^ 1);
        __syncthreads();
        cur ^= 1;
    }

#pragma unroll
    for (int m = 0; m < WM16; m++) {
#pragma unroll
        for (int n = 0; n < WN16; n++) {
            int col = col0 + wc + n * 16 + lrow;
            float bv = HAS_BIAS ? bias[z * zbias + col] : 0.f;
#pragma unroll
            for (int r = 0; r < 4; r++) {
                int row = row0 + wr + m * 16 + kg * 4 + r;
                float v = acc[m][n][r] + bv;
                if (ACT == 1) v = fmaxf(v, 0.f);
                if (ACT == 2) v = (v > 0.f) ? v : expm1f(v);
                size_t ci = (size_t)row * ldc + (size_t)z * zc + col;
                if (OUT_MODE == 0)      ((float*)C)[ci] = v;
                else if (OUT_MODE == 1) ((unsigned short*)C)[ci] = f2bf(v);
                else {
                    if (col < 10)                  esp[row * 10 + col] = v;
                    else if (col >= 16 && col < 26) edp[row * 10 + (col - 16)] = v;
                }
            }
        }
    }
}

// ================= single-buffered template (final head GEMM) ==================
// OUT_MODE: 0 = f32 store, 4 = row-reduce with ca=[N][2] -> C[row*ldc+128/129]+cd
template<int WM16, int WN16, int OUT_MODE, int ACT, int HAS_BIAS>
__global__ __launch_bounds__(256) void mfma_gemm(
    const unsigned short* __restrict__ A, const unsigned short* __restrict__ BT,
    const float* __restrict__ bias, void* __restrict__ C,
    const float* __restrict__ ca, const float* __restrict__ cd,
    int M, int N, int Kpad, int lda, int ldb, int ldc)
{
    constexpr int BM = 32 * WM16, BN = 32 * WN16;
    __shared__ __align__(16) unsigned short Als[BM * 32];
    __shared__ __align__(16) unsigned short Bls[BN * 32];
    const int t = threadIdx.x;
    const int wave = t >> 6, lane = t & 63;
    const int wr = (wave >> 1) * (16 * WM16);
    const int wc = (wave & 1) * (16 * WN16);
    const int row0 = blockIdx.y * BM;
    const int col0 = blockIdx.x * BN;

    f4_t acc[WM16][WN16];
#pragma unroll
    for (int m = 0; m < WM16; m++)
#pragma unroll
        for (int n = 0; n < WN16; n++) { acc[m][n] = (f4_t){0.f, 0.f, 0.f, 0.f}; }

    const int lrow = lane & 15, kg = lane >> 4;
    for (int kk = 0; kk < Kpad; kk += 32) {
        for (int i = t; i < BM * 4; i += 256) {
            int r = i >> 2, slot = i & 3;
            uint4 v = *(const uint4*)&A[(size_t)(row0 + r) * lda + kk + slot * 8];
            *(uint4*)&Als[r * 32 + ((slot ^ (r & 3) ^ ((r >> 2) & 3)) * 8)] = v;
        }
        for (int i = t; i < BN * 4; i += 256) {
            int r = i >> 2, slot = i & 3;
            uint4 v = *(const uint4*)&BT[(size_t)(col0 + r) * ldb + kk + slot * 8];
            *(uint4*)&Bls[r * 32 + ((slot ^ (r & 3) ^ ((r >> 2) & 3)) * 8)] = v;
        }
        __syncthreads();
        frag_t af[WM16], bfr[WN16];
#pragma unroll
        for (int m = 0; m < WM16; m++) {
            int r = wr + m * 16 + lrow;
            af[m] = *(frag_t*)&Als[r * 32 + ((kg ^ (r & 3) ^ ((r >> 2) & 3)) * 8)];
        }
#pragma unroll
        for (int n = 0; n < WN16; n++) {
            int r = wc + n * 16 + lrow;
            bfr[n] = *(frag_t*)&Bls[r * 32 + ((kg ^ (r & 3) ^ ((r >> 2) & 3)) * 8)];
        }
#pragma unroll
        for (int m = 0; m < WM16; m++)
#pragma unroll
            for (int n = 0; n < WN16; n++)
                acc[m][n] = __builtin_amdgcn_mfma_f32_16x16x32_bf16(af[m], bfr[n], acc[m][n], 0, 0, 0);
        __syncthreads();
    }

    if constexpr (OUT_MODE == 0) {
#pragma unroll
        for (int m = 0; m < WM16; m++) {
#pragma unroll
            for (int n = 0; n < WN16; n++) {
                int col = col0 + wc + n * 16 + lrow;
                float bv = HAS_BIAS ? bias[col] : 0.f;
#pragma unroll
                for (int r = 0; r < 4; r++) {
                    int row = row0 + wr + m * 16 + kg * 4 + r;
                    float v = acc[m][n][r] + bv;
                    if (ACT == 1) v = fmaxf(v, 0.f);
                    ((float*)C)[(size_t)row * ldc + col] = v;
                }
            }
        }
    } else {
        __shared__ float o2l[BM][2];
        if (t < BM) { o2l[t][0] = 0.f; o2l[t][1] = 0.f; }
        __syncthreads();
#pragma unroll
        for (int m = 0; m < WM16; m++) {
#pragma unroll
            for (int r = 0; r < 4; r++) {
                int lr = wr + m * 16 + kg * 4 + r;
                float p0 = 0.f, p1 = 0.f;
#pragma unroll
                for (int n = 0; n < WN16; n++) {
                    int col = col0 + wc + n * 16 + lrow;
                    float v = acc[m][n][r] + (HAS_BIAS ? bias[col] : 0.f);
                    if (ACT == 1) v = fmaxf(v, 0.f);
                    p0 = fmaf(v, ca[col * 2], p0);
                    p1 = fmaf(v, ca[col * 2 + 1], p1);
                }
                atomicAdd(&o2l[lr][0], p0);
                atomicAdd(&o2l[lr][1], p1);
            }
        }
        __syncthreads();
        if (t < BM) {
            ((float*)C)[(size_t)(row0 + t) * ldc + 128] = o2l[t][0] + cd[0];
            ((float*)C)[(size_t)(row0 + t) * ldc + 129] = o2l[t][1] + cd[1];
        }
    }
}

// ================= w1_apply: x1[:,h*128:(h+1)*128] = elu(agg_h @ W1h + b1h) ====
__global__ __launch_bounds__(256) void w1_apply(
    const unsigned short* __restrict__ aggb,   // [N,960] bf16, head h at cols h*96
    const unsigned short* __restrict__ W1T,    // [1280,96] bf16
    const float* __restrict__ b1,              // [1280]
    unsigned short* __restrict__ x1)           // [N,1280] bf16
{
    __shared__ __align__(16) unsigned short ls[24576];   // A:[0,12288) B:[12288,24576)
    const int z = blockIdx.y;
    const int row0 = blockIdx.x * 128;
    const int t = threadIdx.x;
    const int wave = t >> 6, lane = t & 63;
    const int wr = (wave >> 1) * 64;
    const int wc = (wave & 1) * 64;
    const int lrow = lane & 15, kg = lane >> 4;

    const unsigned short* A = aggb + (size_t)z * 96;            // lda = 960
    const unsigned short* B = W1T + (size_t)z * 128 * 96;       // ldb = 96

    for (int i = t; i < 1536; i += 256) {
        int r = i / 12, c = i % 12;
        int ks = c >> 2, sl = c & 3;
        int swz = ((sl ^ (r & 3) ^ ((r >> 2) & 3)) * 8);
        uint4 va = *(const uint4*)&A[(size_t)(row0 + r) * 960 + ks * 32 + sl * 8];
        *(uint4*)&ls[(ks * 128 + r) * 32 + swz] = va;
        uint4 vb = *(const uint4*)&B[(size_t)r * 96 + ks * 32 + sl * 8];
        *(uint4*)&ls[12288 + (ks * 128 + r) * 32 + swz] = vb;
    }
    __syncthreads();

    f4_t acc[4][4];
#pragma unroll
    for (int m = 0; m < 4; m++)
#pragma unroll
        for (int n = 0; n < 4; n++) acc[m][n] = (f4_t){0.f, 0.f, 0.f, 0.f};

#pragma unroll
    for (int ks = 0; ks < 3; ks++) {
        frag_t af[4], bfr[4];
#pragma unroll
        for (int m = 0; m < 4; m++) {
            int r = wr + m * 16 + lrow;
            af[m] = *(frag_t*)&ls[(ks * 128 + r) * 32 + ((kg ^ (r & 3) ^ ((r >> 2) & 3)) * 8)];
        }
#pragma unroll
        for (int n = 0; n < 4; n++) {
            int r = wc + n * 16 + lrow;
            bfr[n] = *(frag_t*)&ls[12288 + (ks * 128 + r) * 32 + ((kg ^ (r & 3) ^ ((r >> 2) & 3)) * 8)];
        }
#pragma unroll
        for (int m = 0; m < 4; m++)
#pragma unroll
            for (int n = 0; n < 4; n++)
                acc[m][n] = __builtin_amdgcn_mfma_f32_16x16x32_bf16(af[m], bfr[n], acc[m][n], 0, 0, 0);
    }
    __syncthreads();   // all frag reads done; ls reusable

    // bias + elu, stage bf16 tile [128][128] into ls
#pragma unroll
    for (int m = 0; m < 4; m++) {
#pragma unroll
        for (int n = 0; n < 4; n++) {
            int col = wc + n * 16 + lrow;
            float bv = b1[z * HID + col];
#pragma unroll
            for (int r = 0; r < 4; r++) {
                int lr = wr + m * 16 + kg * 4 + r;
                float v = acc[m][n][r] + bv;
                v = (v > 0.f) ? v : expm1f(v);
                ls[lr * 128 + col] = f2bf(v);
            }
        }
    }
    __syncthreads();

    for (int i = t; i < 2048; i += 256) {
        int r = i >> 4, seg = i & 15;
        *(uint4*)&x1[(size_t)(row0 + r) * F1 + z * HID + seg * 8] =
            *(const uint4*)&ls[r * 128 + seg * 8];
    }
}

// ================= H2 GEMM: double-buffered + fused es2/ed2 + wide store =======
__global__ __launch_bounds__(256) void h2_gemm(
    const unsigned short* __restrict__ A, const unsigned short* __restrict__ BT,
    unsigned short* __restrict__ C,
    const float* __restrict__ as2, const float* __restrict__ ad2,
    float* __restrict__ es2, float* __restrict__ ed2)
{
    __shared__ __align__(16) unsigned short Als[2][32 * 32];
    __shared__ __align__(16) unsigned short Bls[2][128 * 32];
    __shared__ __align__(16) unsigned short ob[32 * 128];
    __shared__ float esl[4][32], edl[4][32];
    const int t = threadIdx.x;
    const int wave = t >> 6, lane = t & 63;
    const int lrow = lane & 15, kg = lane >> 4;
    const int row0 = blockIdx.x * 32;
    const int wc = wave * 32;

    const int ar = t >> 2, asl = t & 3;
    const int br = t >> 2, bsl = t & 3;

    uint4 pa, pb0, pb1;
    auto LOAD = [&](int kk) {
        if (t < 128) pa = *(const uint4*)&A[(size_t)(row0 + ar) * F1 + kk + asl * 8];
        pb0 = *(const uint4*)&BT[(size_t)br * F1 + kk + bsl * 8];
        pb1 = *(const uint4*)&BT[(size_t)(br + 64) * F1 + kk + bsl * 8];
    };
    auto STORE = [&](int buf) {
        if (t < 128)
            *(uint4*)&Als[buf][ar * 32 + ((asl ^ (ar & 3) ^ ((ar >> 2) & 3)) * 8)] = pa;
        *(uint4*)&Bls[buf][br * 32 + ((bsl ^ (br & 3) ^ ((br >> 2) & 3)) * 8)] = pb0;
        int r2 = br + 64;
        *(uint4*)&Bls[buf][r2 * 32 + ((bsl ^ (r2 & 3) ^ ((r2 >> 2) & 3)) * 8)] = pb1;
    };

    LOAD(0);
    STORE(0);
    __syncthreads();

    f4_t acc[2][2];
#pragma unroll
    for (int m = 0; m < 2; m++)
#pragma unroll
        for (int n = 0; n < 2; n++) acc[m][n] = (f4_t){0.f, 0.f, 0.f, 0.f};

    int cur = 0;
    for (int ks = 0; ks < 40; ks++) {
        if (ks < 39) LOAD((ks + 1) * 32);
        frag_t af[2], bfr[2];
#pragma unroll
        for (int m = 0; m < 2; m++) {
            int r = m * 16 + lrow;
            af[m] = *(frag_t*)&Als[cur][r * 32 + ((kg ^ (r & 3) ^ ((r >> 2) & 3)) * 8)];
        }
#pragma unroll
        for (int n = 0; n < 2; n++) {
            int r = wc + n * 16 + lrow;
            bfr[n] = *(frag_t*)&Bls[cur][r * 32 + ((kg ^ (r & 3) ^ ((r >> 2) & 3)) * 8)];
        }
#pragma unroll
        for (int m = 0; m < 2; m++)
#pragma unroll
            for (int n = 0; n < 2; n++)
                acc[m][n] = __builtin_amdgcn_mfma_f32_16x16x32_bf16(af[m], bfr[n], acc[m][n], 0, 0, 0);
        if (ks < 39) STORE(cur ^ 1);
        __syncthreads();
        cur ^= 1;
    }

#pragma unroll
    for (int m = 0; m < 2; m++) {
#pragma unroll
        for (int r = 0; r < 4; r++) {
            int lr = m * 16 + kg * 4 + r;
            float pes = 0.f, ped = 0.f;
#pragma unroll
            for (int n = 0; n < 2; n++) {
                int col = wc + n * 16 + lrow;
                float v = acc[m][n][r];
                ob[lr * 128 + col] = f2bf(v);
                pes = fmaf(v, as2[col], pes);
                ped = fmaf(v, ad2[col], ped);
            }
#pragma unroll
            for (int o = 1; o < 16; o <<= 1) {
                pes += __shfl_xor(pes, o);
                ped += __shfl_xor(ped, o);
            }
            if (lrow == 0) { esl[wave][lr] = pes; edl[wave][lr] = ped; }
        }
    }
    __syncthreads();
    for (int i = t; i < 512; i += 256) {
        int r = i >> 4, seg = i & 15;
        *(uint4*)&C[(size_t)(row0 + r) * HID + seg * 8] = *(const uint4*)&ob[r * 128 + seg * 8];
    }
    if (t < 32) {
        es2[row0 + t] = esl[0][t] + esl[1][t] + esl[2][t] + esl[3][t];
        ed2[row0 + t] = edl[0][t] + edl[1][t] + edl[2][t] + edl[3][t];
    }
}

// ======= pool_head: out[:,0:128] = relu(decode(pk) @ Wg + bg), K=128 in LDS ====
// grid BGRAPH/64 = 4 blocks, 256 thr; fuses key-decode + Wg GEMM + direct store.
__global__ __launch_bounds__(256) void pool_head(
    const unsigned* __restrict__ pk, const unsigned short* __restrict__ WgT,
    const float* __restrict__ bg, float* __restrict__ out)
{
    __shared__ __align__(16) unsigned short Als[64 * 128];    // 16 KB
    __shared__ __align__(16) unsigned short Bls[128 * 128];   // 32 KB
    const int t = threadIdx.x;
    const int wave = t >> 6, lane = t & 63;
    const int lrow = lane & 15, kg = lane >> 4;
    const int row0 = blockIdx.x * 64;
    const int wr = (wave >> 1) * 32;
    const int wc = (wave & 1) * 64;

    // stage A: decode pk -> bf16 pairs, k-step-partitioned swizzled layout
    for (int i = t; i < 4096; i += 256) {
        int r = i >> 6, k0 = (i & 63) * 2;
        int ks = k0 >> 5, cw = k0 & 31, slot = cw >> 3, elem = cw & 7;
        unsigned lo = f2bf(funkey(pk[(row0 + r) * HID + k0]));
        unsigned hi = f2bf(funkey(pk[(row0 + r) * HID + k0 + 1]));
        *(unsigned*)&Als[(ks * 64 + r) * 32 + ((slot ^ (r & 3) ^ ((r >> 2) & 3)) * 8) + elem]
            = lo | (hi << 16);
    }
    // stage B: WgT [128,128]
    for (int i = t; i < 2048; i += 256) {
        int r = i >> 4, c = i & 15;
        int ks = c >> 2, sl = c & 3;
        uint4 v = *(const uint4*)&WgT[(size_t)r * HID + ks * 32 + sl * 8];
        *(uint4*)&Bls[(ks * 128 + r) * 32 + ((sl ^ (r & 3) ^ ((r >> 2) & 3)) * 8)] = v;
    }
    __syncthreads();

    f4_t acc[2][4];
#pragma unroll
    for (int m = 0; m < 2; m++)
#pragma unroll
        for (int n = 0; n < 4; n++) acc[m][n] = (f4_t){0.f, 0.f, 0.f, 0.f};

#pragma unroll
    for (int ks = 0; ks < 4; ks++) {
        frag_t af[2], bfr[4];
#pragma unroll
        for (int m = 0; m < 2; m++) {
            int r = wr + m * 16 + lrow;
            af[m] = *(frag_t*)&Als[(ks * 64 + r) * 32 + ((kg ^ (r & 3) ^ ((r >> 2) & 3)) * 8)];
        }
#pragma unroll
        for (int n = 0; n < 4; n++) {
            int r = wc + n * 16 + lrow;
            bfr[n] = *(frag_t*)&Bls[(ks * 128 + r) * 32 + ((kg ^ (r & 3) ^ ((r >> 2) & 3)) * 8)];
        }
#pragma unroll
        for (int m = 0; m < 2; m++)
#pragma unroll
            for (int n = 0; n < 4; n++)
                acc[m][n] = __builtin_amdgcn_mfma_f32_16x16x32_bf16(af[m], bfr[n], acc[m][n], 0, 0, 0);
    }

#pragma unroll
    for (int m = 0; m < 2; m++) {
#pragma unroll
        for (int n = 0; n < 4; n++) {
            int col = wc + n * 16 + lrow;
            float bv = bg[col];
#pragma unroll
            for (int r = 0; r < 4; r++) {
                int row = row0 + wr + m * 16 + kg * 4 + r;
                out[(size_t)row * 130 + col] = fmaxf(acc[m][n][r] + bv, 0.f);
            }
        }
    }
}

// ======= mega prep: converts + transposes + fold + zero-pk + hist + cell-norm ==
#define S0 1572864   // xb: 16384*96
#define S1 122880    // W1T: 1280*96
#define S2 163840    // W2T: 128*1280
#define S3 1966080   // Wf1T: 2048*960
#define S4 1048576   // Wf2T: 512*2048
#define S5 65536     // Wf3T: 128*512
#define S6 16384     // WgT: 128*128
#define PREP_TOTAL (S0+S1+S2+S3+S4+S5+S6)   // 4956160 = 19360*256
#define NB_ELEM (PREP_TOTAL / 256)          // 19360
#define NB_FOLD 768                          // 3072 fold entries, 4 waves/block
#define NB_ZPK  128                          // pk: 32768
#define NB_HIST ((ETOT + 255) / 256)         // 576
#define NB_CELL BGRAPH                       // 256 cell rows

__global__ void prep_all(const float* __restrict__ x,  const float* __restrict__ W1,
                         const float* __restrict__ W2, const float* __restrict__ Wf1,
                         const float* __restrict__ Wf2, const float* __restrict__ Wf3,
                         const float* __restrict__ Wg,
                         const float* __restrict__ as1, const float* __restrict__ ad1,
                         const int* __restrict__ ei, const float* __restrict__ cell,
                         unsigned short* __restrict__ xb,  unsigned short* __restrict__ W1T,
                         unsigned short* __restrict__ W2T, unsigned short* __restrict__ Wf1T,
                         unsigned short* __restrict__ Wf2T, unsigned short* __restrict__ Wf3T,
                         unsigned short* __restrict__ WgT, unsigned short* __restrict__ F1T,
                         int* __restrict__ counts, unsigned* __restrict__ pk,
                         unsigned short* __restrict__ celln)
{
    int blk = blockIdx.x, t = threadIdx.x;
    if (blk < NB_ELEM) {
        int i = blk * 256 + t;
        if (i < S0) { int r = i / 96, k = i % 96;
            xb[i] = (k < F_INPUT) ? f2bf(x[r * F_INPUT + k]) : 0; return; }
        i -= S0;
        if (i < S1) { int n = i / 96, k = i % 96;
            W1T[i] = (k < F_INPUT) ? f2bf(W1[(size_t)k * F1 + n]) : 0; return; }
        i -= S1;
        if (i < S2) { int n = i / 1280, k = i % 1280;
            W2T[i] = f2bf(W2[(size_t)k * HID + n]); return; }
        i -= S2;
        if (i < S3) { int n = i / 960, k = i % 960;
            Wf1T[i] = (k < F_CELL) ? f2bf(Wf1[(size_t)k * 2048 + n]) : 0; return; }
        i -= S3;
        if (i < S4) { int n = i / 2048, k = i % 2048;
            Wf2T[i] = f2bf(Wf2[(size_t)k * 512 + n]); return; }
        i -= S4;
        if (i < S5) { int n = i / 512, k = i % 512;
            Wf3T[i] = f2bf(Wf3[(size_t)k * HID + n]); return; }
        i -= S5;
        { int n = i / 128, k = i % 128;
            WgT[i] = f2bf(Wg[(size_t)k * HID + n]); }
        return;
    }
    blk -= NB_ELEM;
    if (blk < NB_FOLD) {
        int idx = blk * 4 + (t >> 6);
        int l = t & 63;
        int r = idx / 96, k = idx % 96;
        int sd = r >> 4, h = r & 15;
        float p = 0.f;
        if (h < HEADS && k < F_INPUT) {
            const float* a = (sd ? ad1 : as1) + h * HID;
            float2 wv = *(const float2*)&W1[(size_t)k * F1 + h * HID + 2 * l];
            float2 av = *(const float2*)&a[2 * l];
            p = wv.x * av.x + wv.y * av.y;
#pragma unroll
            for (int o = 32; o > 0; o >>= 1) p += __shfl_xor(p, o);
        }
        if (l == 0) F1T[(size_t)r * 96 + k] = f2bf(p);
        return;
    }
    blk -= NB_FOLD;
    if (blk < NB_ZPK) { pk[blk * 256 + t] = 0; return; }   // 0 < fkey(any float)
    blk -= NB_ZPK;
    if (blk < NB_HIST) {
        int e = blk * 256 + t;
        if (e < ETOT) {
            int dst = (e < E_EDGES) ? ei[E_EDGES + e] : (e - E_EDGES);
            atomicAdd(&counts[dst], 1);
        }
        return;
    }
    blk -= NB_HIST;
    // cell L2-normalize (one block per row)
    {
        int b = blk;
        __shared__ float red[256];
        float s = 0.f;
        for (int c = t; c < F_CELL; c += 256) { float v = cell[(size_t)b * F_CELL + c]; s += v * v; }
        red[t] = s; __syncthreads();
        for (int o = 128; o > 0; o >>= 1) { if (t < o) red[t] += red[t + o]; __syncthreads(); }
        float inv = 1.f / fmaxf(sqrtf(red[0]), 1e-12f);
        for (int c = t; c < KPADC; c += 256) {
            float v = (c < F_CELL) ? cell[(size_t)b * F_CELL + c] * inv : 0.f;
            celln[(size_t)b * KPADC + c] = f2bf(v);
        }
    }
}

// ================= CSR scan (vectorized) + scatter =================
__global__ void scan_counts(const int* __restrict__ counts,
                            int* __restrict__ row_start, int* __restrict__ cursor)
{
    __shared__ int part[256];
    int t = threadIdx.x;
    int base = t * 64;
    int4 v[16];
#pragma unroll
    for (int i = 0; i < 16; i++) v[i] = *(const int4*)&counts[base + i * 4];
    int sum = 0;
#pragma unroll
    for (int i = 0; i < 16; i++) sum += v[i].x + v[i].y + v[i].z + v[i].w;
    part[t] = sum;
    __syncthreads();
    for (int o = 1; o < 256; o <<= 1) {
        int vv = (t >= o) ? part[t - o] : 0;
        __syncthreads();
        part[t] += vv;
        __syncthreads();
    }
    int run = (t == 0) ? 0 : part[t - 1];
#pragma unroll
    for (int i = 0; i < 16; i++) {
        int4 w;
        w.x = run; run += v[i].x;
        w.y = run; run += v[i].y;
        w.z = run; run += v[i].z;
        w.w = run; run += v[i].w;
        *(int4*)&row_start[base + i * 4] = w;
        *(int4*)&cursor[base + i * 4] = w;
    }
    if (t == 255) row_start[N_NODES] = run;
}

__global__ void scatter_csr(const int* __restrict__ ei, int* __restrict__ cursor,
                            int* __restrict__ csr_src)
{
    int e = blockIdx.x * blockDim.x + threadIdx.x;
    if (e >= ETOT) return;
    int src, dst;
    if (e < E_EDGES) { src = ei[e]; dst = ei[E_EDGES + e]; } else { src = dst = e - E_EDGES; }
    int pos = atomicAdd(&cursor[dst], 1);
    csr_src[pos] = src;
}

// ================= GAT layer-1 aggregation over RAW x (96 bf16 per row) ========
__global__ __launch_bounds__(256) void gat1_agg(
    const int* __restrict__ row_start, const int* __restrict__ csr_src,
    const unsigned* __restrict__ xb32,          // [N,48] u32 = 96 bf16
    const float* __restrict__ es, const float* __restrict__ ed,
    unsigned* __restrict__ aggb)                // [N,480] u32 = 960 bf16
{
    const int w = threadIdx.x >> 6, l = threadIdx.x & 63;
    const int n = blockIdx.x * 4 + w;
    const int rs = row_start[n];
    const int deg = row_start[n + 1] - rs;

    __shared__ __align__(16) float w_lds[4][64][12];
    __shared__ int src_lds[4][64];

    float edv[HEADS];
    const float* edp = ed + n * HEADS;
#pragma unroll
    for (int h = 0; h < HEADS; h++) edv[h] = edp[h];

    float acc0[HEADS], acc1[HEADS], den[HEADS];
#pragma unroll
    for (int h = 0; h < HEADS; h++) { acc0[h] = 0.f; acc1[h] = 0.f; den[h] = 0.f; }

    for (int base = 0; base < deg; base += 64) {
        int e = base + l;
        int cnt = min(64, deg - base);
        float wv[HEADS];
        if (e < deg) {
            int s = csr_src[rs + e];
            src_lds[w][l] = s;
            const float* ep = es + s * HEADS;
#pragma unroll
            for (int h = 0; h < HEADS; h++) {
                float v = ep[h] + edv[h];
                v = (v >= 0.f) ? v : NEG_SLOPE * v;
                wv[h] = __expf(v);
            }
        } else {
#pragma unroll
            for (int h = 0; h < HEADS; h++) wv[h] = 0.f;
        }
#pragma unroll
        for (int h = 0; h < HEADS; h++) {
            den[h] += wv[h];
            w_lds[w][l][h] = wv[h];
        }
        asm volatile("" ::: "memory");

        for (int j = 0; j < cnt; j++) {
            int sj = src_lds[w][j];
            unsigned xv = 0;
            if (l < 48) xv = xb32[(size_t)sj * 48 + l];
            float x0 = bf2f((unsigned short)(xv & 0xffffu));
            float x1v = bf2f((unsigned short)(xv >> 16));
            float4 wa = *(const float4*)&w_lds[w][j][0];
            float4 wb = *(const float4*)&w_lds[w][j][4];
            float2 wcv = *(const float2*)&w_lds[w][j][8];
            float ww[HEADS] = {wa.x, wa.y, wa.z, wa.w, wb.x, wb.y, wb.z, wb.w, wcv.x, wcv.y};
#pragma unroll
            for (int h = 0; h < HEADS; h++) {
                acc0[h] = fmaf(ww[h], x0, acc0[h]);
                acc1[h] = fmaf(ww[h], x1v, acc1[h]);
            }
        }
        asm volatile("" ::: "memory");
    }

#pragma unroll
    for (int h = 0; h < HEADS; h++)
#pragma unroll
        for (int o = 32; o > 0; o >>= 1) den[h] += __shfl_xor(den[h], o);

    if (l < 48) {
        unsigned* orow = aggb + (size_t)n * 480;
#pragma unroll
        for (int h = 0; h < HEADS; h++) {
            float inv = 1.f / den[h];
            unsigned lo = f2bf(acc0[h] * inv);
            unsigned hi = f2bf(acc1[h] * inv);
            orow[h * 48 + l] = lo | (hi << 16);
        }
    }
}

// ================= GAT layer-2 aggregation + fused graph max-pool ==============
__global__ __launch_bounds__(256) void gat2_agg(
    const int* __restrict__ row_start, const int* __restrict__ csr_src,
    const unsigned short* __restrict__ H2,
    const float* __restrict__ es, const float* __restrict__ ed,
    const float* __restrict__ b, const int* __restrict__ batch,
    unsigned* __restrict__ pk)
{
    const int w = threadIdx.x >> 6, l = threadIdx.x & 63;
    const int n = blockIdx.x * 4 + w;
    const int rs = row_start[n];
    const int deg = row_start[n + 1] - rs;
    const float edv = ed[n];

    float2 acc = {0.f, 0.f};
    float den = 0.f;
    for (int base = 0; base < deg; base += 64) {
        int e = base + l;
        int cnt = min(64, deg - base);
        int s = 0;
        float wv = 0.f;
        if (e < deg) {
            s = csr_src[rs + e];
            float v = es[s] + edv;
            v = (v >= 0.f) ? v : NEG_SLOPE * v;
            wv = __expf(v);
        }
        den += wv;
        for (int j = 0; j < cnt; j++) {
            float wj = __shfl(wv, j);
            int   sj = __shfl(s, j);
            unsigned hp = *(const unsigned*)&H2[(size_t)sj * HID + 2 * l];
            acc.x = fmaf(wj, bf2f((unsigned short)(hp & 0xffffu)), acc.x);
            acc.y = fmaf(wj, bf2f((unsigned short)(hp >> 16)), acc.y);
        }
    }
#pragma unroll
    for (int o = 32; o > 0; o >>= 1) den += __shfl_xor(den, o);

    float inv = 1.f / den;
    float2 bv = *(const float2*)&b[2 * l];
    float v0 = acc.x * inv + bv.x;
    float v1 = acc.y * inv + bv.y;
    v0 = (v0 > 0.f) ? v0 : expm1f(v0);
    v1 = (v1 > 0.f) ? v1 : expm1f(v1);
    int g = batch[n];
    atomicMax(&pk[g * HID + 2 * l], fkey(v0));
    atomicMax(&pk[g * HID + 2 * l + 1], fkey(v1));
}

extern "C" void kernel_launch(void* const* d_in, const int* in_sizes, int n_in,
                              void* d_out, int out_size, void* d_ws, size_t ws_size,
                              hipStream_t stream)
{
    const float* x    = (const float*)d_in[0];
    const int*   ei   = (const int*)d_in[1];
    const int*   batch= (const int*)d_in[2];
    const float* cell = (const float*)d_in[3];
    const float* W1   = (const float*)d_in[4];
    const float* as1  = (const float*)d_in[5];
    const float* ad1  = (const float*)d_in[6];
    const float* b1   = (const float*)d_in[7];
    const float* W2   = (const float*)d_in[8];
    const float* as2  = (const float*)d_in[9];
    const float* ad2  = (const float*)d_in[10];
    const float* b2   = (const float*)d_in[11];
    const float* Wg   = (const float*)d_in[12];
    const float* bg   = (const float*)d_in[13];
    const float* Wf1  = (const float*)d_in[14];
    const float* bf1  = (const float*)d_in[15];
    const float* Wf2  = (const float*)d_in[16];
    const float* bf2  = (const float*)d_in[17];
    const float* Wf3  = (const float*)d_in[18];
    const float* bf3  = (const float*)d_in[19];
    const float* Wo   = (const float*)d_in[20];
    const float* bo   = (const float*)d_in[21];
    float* out = (float*)d_out;

    char* w = (char*)d_ws;
    auto alloc = [&](size_t bytes) { char* p = w; w += (bytes + 255) & ~(size_t)255; return p; };
    unsigned short* xb   = (unsigned short*)alloc((size_t)N_NODES * KPAD1 * 2);   // 3.1 MB
    unsigned short* W1T  = (unsigned short*)alloc((size_t)F1 * KPAD1 * 2);
    unsigned short* F1T  = (unsigned short*)alloc((size_t)32 * KPAD1 * 2);
    unsigned*       aggb = (unsigned*)alloc((size_t)N_NODES * 480 * 4);           // 31.5 MB
    unsigned short* x1   = (unsigned short*)alloc((size_t)N_NODES * F1 * 2);      // 42 MB
    unsigned short* W2T  = (unsigned short*)alloc((size_t)HID * F1 * 2);
    unsigned short* H2   = (unsigned short*)alloc((size_t)N_NODES * HID * 2);     // 4.2 MB
    float*    es1  = (float*)alloc((size_t)N_NODES * HEADS * 4);
    float*    ed1  = (float*)alloc((size_t)N_NODES * HEADS * 4);
    float*    es2  = (float*)alloc((size_t)N_NODES * 4);
    float*    ed2  = (float*)alloc((size_t)N_NODES * 4);
    int*      counts    = (int*)alloc((size_t)N_NODES * 4);
    int*      row_start = (int*)alloc((size_t)(N_NODES + 1) * 4);
    int*      cursor    = (int*)alloc((size_t)N_NODES * 4);
    int*      csr_src   = (int*)alloc((size_t)ETOT * 4);
    unsigned* pk   = (unsigned*)alloc((size_t)BGRAPH * HID * 4);
    unsigned short* WgT  = (unsigned short*)alloc((size_t)HID * HID * 2);
    unsigned short* celln = (unsigned short*)alloc((size_t)BGRAPH * KPADC * 2);
    unsigned short* Wf1T = (unsigned short*)alloc((size_t)2048 * KPADC * 2);
    unsigned short* Wf2T = (unsigned short*)alloc((size_t)512 * 2048 * 2);
    unsigned short* Wf3T = (unsigned short*)alloc((size_t)HID * 512 * 2);
    unsigned short* xc1b = (unsigned short*)alloc((size_t)BGRAPH * 2048 * 2);
    unsigned short* xc2b = (unsigned short*)alloc((size_t)BGRAPH * 512 * 2);

    dim3 b256(256);

    // 0. zero counts (hist runs inside prep_all)
    hipMemsetAsync(counts, 0, (size_t)N_NODES * 4, stream);

    // 1. all prep: converts, transposes, a-fold, zero pk, dst-hist, cell-norm
    prep_all<<<NB_ELEM + NB_FOLD + NB_ZPK + NB_HIST + NB_CELL, b256, 0, stream>>>(
        x, W1, W2, Wf1, Wf2, Wf3, Wg, as1, ad1, ei, cell,
        xb, W1T, W2T, Wf1T, Wf2T, Wf3T, WgT, F1T, counts, pk, celln);

    // 2-3. CSR scan + scatter
    scan_counts<<<1, b256, 0, stream>>>(counts, row_start, cursor);
    scatter_csr<<<(ETOT + 255) / 256, b256, 0, stream>>>(ei, cursor, csr_src);

    // 4. layer-1 coefs: es1/ed1 = x @ folded-a  (db pipeline, 256 blocks)
    gemm_db<2, 1, 2, 0, 0><<<dim3(1, N_NODES / 64), b256, 0, stream>>>(
        xb, F1T, nullptr, nullptr, es1, ed1,
        N_NODES, 32, KPAD1, KPAD1, KPAD1, 32, 0, 0, 0, 0);

    // 5. aggregate raw x per head
    gat1_agg<<<N_NODES / 4, b256, 0, stream>>>(row_start, csr_src, (const unsigned*)xb,
                                               es1, ed1, aggb);

    // 6. x1 = elu(agg @ W1 + b1), per head; LDS-wide stores (no write amp)
    w1_apply<<<dim3(N_NODES / 128, HEADS), b256, 0, stream>>>(
        (const unsigned short*)aggb, W1T, b1, x1);

    // 7. H2 = x1 @ W2 (db pipeline) + fused es2/ed2 + wide store
    h2_gemm<<<N_NODES / 32, b256, 0, stream>>>(x1, W2T, H2, as2, ad2, es2, ed2);

    // 8. layer-2 aggregation + fused graph max-pool
    gat2_agg<<<N_NODES / 4, b256, 0, stream>>>(row_start, csr_src, H2, es2, ed2, b2,
                                               batch, pk);

    // 9. out[:,0:128] = relu(decode(pk) @ Wg + bg)  (fused decode + GEMM)
    pool_head<<<BGRAPH / 64, b256, 0, stream>>>(pk, WgT, bg, out);

    // 10-11. cell branch (db pipeline)
    gemm_db<1, 2, 1, 1, 1><<<dim3(2048 / 64, BGRAPH / 32), b256, 0, stream>>>(
        celln, Wf1T, bf1, xc1b, nullptr, nullptr,
        BGRAPH, 2048, KPADC, KPADC, KPADC, 2048, 0, 0, 0, 0);
    gemm_db<1, 2, 1, 1, 1><<<dim3(512 / 64, BGRAPH / 32), b256, 0, stream>>>(
        xc1b, Wf2T, bf2, xc2b, nullptr, nullptr,
        BGRAPH, 512, 2048, 2048, 2048, 512, 0, 0, 0, 0);

    // 12. xc3 = relu(xc2 @ Wf3 + bf3); out[:,128:130] = xc3 @ Wo + bo  (fused)
    mfma_gemm<1, 4, 4, 1, 1><<<dim3(1, BGRAPH / 32), b256, 0, stream>>>(
        xc2b, Wf3T, bf3, out, Wo, bo,
        BGRAPH, HID, 512, 512, 512, 130);
}

// Round 17
// 214.209 us; speedup vs baseline: 1.2935x; 1.0523x over previous
//
#include <hip/hip_runtime.h>
#include <hip/hip_bf16.h>
#include <math.h>

#define N_NODES 16384
#define E_EDGES 131072
#define ETOT (E_EDGES + N_NODES)   // 147456 (self-loops appended)
#define BGRAPH 256
#define F_INPUT 78
#define KPAD1 96                   // F_INPUT padded to mult of 32
#define HID 128
#define HEADS 10
#define F1 (HEADS * HID)           // 1280
#define F_CELL 954
#define KPADC 960                  // F_CELL padded
#define NEG_SLOPE 0.2f

typedef __attribute__((ext_vector_type(8))) short frag_t;   // 8 bf16
typedef __attribute__((ext_vector_type(4))) float f4_t;

static __device__ __forceinline__ unsigned fkey(float f) {
    unsigned b = __float_as_uint(f);
    return (b & 0x80000000u) ? ~b : (b | 0x80000000u);
}
static __device__ __forceinline__ float funkey(unsigned k) {
    unsigned b = (k & 0x80000000u) ? (k ^ 0x80000000u) : ~k;
    return __uint_as_float(b);
}
static __device__ __forceinline__ unsigned short f2bf(float f) {
    __hip_bfloat16 h = __float2bfloat16(f);
    return *(unsigned short*)&h;
}
static __device__ __forceinline__ float bf2f(unsigned short u) {
    return __uint_as_float(((unsigned)u) << 16);
}

// ======== gemm_db: 2-phase double-buffered MFMA GEMM (reg prefetch) ============
// OUT_MODE: 0 = f32 store, 1 = bf16 store,
//           2 = coef1 scatter (cols 0..9 -> esp, 16..25 -> edp)
// ACT: 0 none, 1 relu, 2 elu.
template<int WM16, int WN16, int OUT_MODE, int ACT, int HAS_BIAS>
__global__ __launch_bounds__(256) void gemm_db(
    const unsigned short* __restrict__ A, const unsigned short* __restrict__ BT,
    const float* __restrict__ bias, void* __restrict__ C,
    float* __restrict__ esp, float* __restrict__ edp,
    int M, int N, int K, int lda, int ldb, int ldc,
    int za, int zb, int zc, int zbias)
{
    constexpr int BM = 32 * WM16, BN = 32 * WN16;
    constexpr int LA = BM * 4;
    constexpr int LB = BN * 4;
    constexpr int NA = (LA + 255) / 256;
    constexpr int NB = (LB + 255) / 256;
    __shared__ __align__(16) unsigned short Als[2][BM * 32];
    __shared__ __align__(16) unsigned short Bls[2][BN * 32];
    const int z = blockIdx.z;
    A  += (size_t)z * za;
    BT += (size_t)z * zb;
    const int t = threadIdx.x;
    const int wave = t >> 6, lane = t & 63;
    const int wr = (wave >> 1) * (16 * WM16);
    const int wc = (wave & 1) * (16 * WN16);
    const int row0 = blockIdx.y * BM;
    const int col0 = blockIdx.x * BN;
    const int lrow = lane & 15, kg = lane >> 4;

    uint4 pa[NA], pb[NB];
    auto LOAD = [&](int kk) {
#pragma unroll
        for (int i = 0; i < NA; i++) { int idx = t + i * 256; if (idx < LA) {
            int r = idx >> 2, sl = idx & 3;
            pa[i] = *(const uint4*)&A[(size_t)(row0 + r) * lda + kk + sl * 8]; } }
#pragma unroll
        for (int i = 0; i < NB; i++) { int idx = t + i * 256; if (idx < LB) {
            int r = idx >> 2, sl = idx & 3;
            pb[i] = *(const uint4*)&BT[(size_t)(col0 + r) * ldb + kk + sl * 8]; } }
    };
    auto STORE = [&](int buf) {
#pragma unroll
        for (int i = 0; i < NA; i++) { int idx = t + i * 256; if (idx < LA) {
            int r = idx >> 2, sl = idx & 3;
            *(uint4*)&Als[buf][r * 32 + ((sl ^ (r & 3) ^ ((r >> 2) & 3)) * 8)] = pa[i]; } }
#pragma unroll
        for (int i = 0; i < NB; i++) { int idx = t + i * 256; if (idx < LB) {
            int r = idx >> 2, sl = idx & 3;
            *(uint4*)&Bls[buf][r * 32 + ((sl ^ (r & 3) ^ ((r >> 2) & 3)) * 8)] = pb[i]; } }
    };

    f4_t acc[WM16][WN16];
#pragma unroll
    for (int m = 0; m < WM16; m++)
#pragma unroll
        for (int n = 0; n < WN16; n++) acc[m][n] = (f4_t){0.f, 0.f, 0.f, 0.f};

    LOAD(0);
    STORE(0);
    __syncthreads();

    const int nk = K / 32;
    int cur = 0;
    for (int ks = 0; ks < nk; ks++) {
        if (ks < nk - 1) LOAD((ks + 1) * 32);
        frag_t af[WM16], bfr[WN16];
#pragma unroll
        for (int m = 0; m < WM16; m++) {
            int r = wr + m * 16 + lrow;
            af[m] = *(frag_t*)&Als[cur][r * 32 + ((kg ^ (r & 3) ^ ((r >> 2) & 3)) * 8)];
        }
#pragma unroll
        for (int n = 0; n < WN16; n++) {
            int r = wc + n * 16 + lrow;
            bfr[n] = *(frag_t*)&Bls[cur][r * 32 + ((kg ^ (r & 3) ^ ((r >> 2) & 3)) * 8)];
        }
#pragma unroll
        for (int m = 0; m < WM16; m++)
#pragma unroll
            for (int n = 0; n < WN16; n++)
                acc[m][n] = __builtin_amdgcn_mfma_f32_16x16x32_bf16(af[m], bfr[n], acc[m][n], 0, 0, 0);
        if (ks < nk - 1) STORE(cur ^ 1);
        __syncthreads();
        cur ^= 1;
    }

#pragma unroll
    for (int m = 0; m < WM16; m++) {
#pragma unroll
        for (int n = 0; n < WN16; n++) {
            int col = col0 + wc + n * 16 + lrow;
            float bv = HAS_BIAS ? bias[z * zbias + col] : 0.f;
#pragma unroll
            for (int r = 0; r < 4; r++) {
                int row = row0 + wr + m * 16 + kg * 4 + r;
                float v = acc[m][n][r] + bv;
                if (ACT == 1) v = fmaxf(v, 0.f);
                if (ACT == 2) v = (v > 0.f) ? v : expm1f(v);
                size_t ci = (size_t)row * ldc + (size_t)z * zc + col;
                if (OUT_MODE == 0)      ((float*)C)[ci] = v;
                else if (OUT_MODE == 1) ((unsigned short*)C)[ci] = f2bf(v);
                else {
                    if (col < 10)                  esp[row * 10 + col] = v;
                    else if (col >= 16 && col < 26) edp[row * 10 + (col - 16)] = v;
                }
            }
        }
    }
}

// ================= single-buffered template (final head GEMM) ==================
// OUT_MODE: 0 = f32 store, 4 = row-reduce with ca=[N][2] -> C[row*ldc+128/129]+cd
template<int WM16, int WN16, int OUT_MODE, int ACT, int HAS_BIAS>
__global__ __launch_bounds__(256) void mfma_gemm(
    const unsigned short* __restrict__ A, const unsigned short* __restrict__ BT,
    const float* __restrict__ bias, void* __restrict__ C,
    const float* __restrict__ ca, const float* __restrict__ cd,
    int M, int N, int Kpad, int lda, int ldb, int ldc)
{
    constexpr int BM = 32 * WM16, BN = 32 * WN16;
    __shared__ __align__(16) unsigned short Als[BM * 32];
    __shared__ __align__(16) unsigned short Bls[BN * 32];
    const int t = threadIdx.x;
    const int wave = t >> 6, lane = t & 63;
    const int wr = (wave >> 1) * (16 * WM16);
    const int wc = (wave & 1) * (16 * WN16);
    const int row0 = blockIdx.y * BM;
    const int col0 = blockIdx.x * BN;

    f4_t acc[WM16][WN16];
#pragma unroll
    for (int m = 0; m < WM16; m++)
#pragma unroll
        for (int n = 0; n < WN16; n++) { acc[m][n] = (f4_t){0.f, 0.f, 0.f, 0.f}; }

    const int lrow = lane & 15, kg = lane >> 4;
    for (int kk = 0; kk < Kpad; kk += 32) {
        for (int i = t; i < BM * 4; i += 256) {
            int r = i >> 2, slot = i & 3;
            uint4 v = *(const uint4*)&A[(size_t)(row0 + r) * lda + kk + slot * 8];
            *(uint4*)&Als[r * 32 + ((slot ^ (r & 3) ^ ((r >> 2) & 3)) * 8)] = v;
        }
        for (int i = t; i < BN * 4; i += 256) {
            int r = i >> 2, slot = i & 3;
            uint4 v = *(const uint4*)&BT[(size_t)(col0 + r) * ldb + kk + slot * 8];
            *(uint4*)&Bls[r * 32 + ((slot ^ (r & 3) ^ ((r >> 2) & 3)) * 8)] = v;
        }
        __syncthreads();
        frag_t af[WM16], bfr[WN16];
#pragma unroll
        for (int m = 0; m < WM16; m++) {
            int r = wr + m * 16 + lrow;
            af[m] = *(frag_t*)&Als[r * 32 + ((kg ^ (r & 3) ^ ((r >> 2) & 3)) * 8)];
        }
#pragma unroll
        for (int n = 0; n < WN16; n++) {
            int r = wc + n * 16 + lrow;
            bfr[n] = *(frag_t*)&Bls[r * 32 + ((kg ^ (r & 3) ^ ((r >> 2) & 3)) * 8)];
        }
#pragma unroll
        for (int m = 0; m < WM16; m++)
#pragma unroll
            for (int n = 0; n < WN16; n++)
                acc[m][n] = __builtin_amdgcn_mfma_f32_16x16x32_bf16(af[m], bfr[n], acc[m][n], 0, 0, 0);
        __syncthreads();
    }

    if constexpr (OUT_MODE == 0) {
#pragma unroll
        for (int m = 0; m < WM16; m++) {
#pragma unroll
            for (int n = 0; n < WN16; n++) {
                int col = col0 + wc + n * 16 + lrow;
                float bv = HAS_BIAS ? bias[col] : 0.f;
#pragma unroll
                for (int r = 0; r < 4; r++) {
                    int row = row0 + wr + m * 16 + kg * 4 + r;
                    float v = acc[m][n][r] + bv;
                    if (ACT == 1) v = fmaxf(v, 0.f);
                    ((float*)C)[(size_t)row * ldc + col] = v;
                }
            }
        }
    } else {
        __shared__ float o2l[BM][2];
        if (t < BM) { o2l[t][0] = 0.f; o2l[t][1] = 0.f; }
        __syncthreads();
#pragma unroll
        for (int m = 0; m < WM16; m++) {
#pragma unroll
            for (int r = 0; r < 4; r++) {
                int lr = wr + m * 16 + kg * 4 + r;
                float p0 = 0.f, p1 = 0.f;
#pragma unroll
                for (int n = 0; n < WN16; n++) {
                    int col = col0 + wc + n * 16 + lrow;
                    float v = acc[m][n][r] + (HAS_BIAS ? bias[col] : 0.f);
                    if (ACT == 1) v = fmaxf(v, 0.f);
                    p0 = fmaf(v, ca[col * 2], p0);
                    p1 = fmaf(v, ca[col * 2 + 1], p1);
                }
                atomicAdd(&o2l[lr][0], p0);
                atomicAdd(&o2l[lr][1], p1);
            }
        }
        __syncthreads();
        if (t < BM) {
            ((float*)C)[(size_t)(row0 + t) * ldc + 128] = o2l[t][0] + cd[0];
            ((float*)C)[(size_t)(row0 + t) * ldc + 129] = o2l[t][1] + cd[1];
        }
    }
}

// ================= w1_apply: x1[:,h*128:(h+1)*128] = elu(agg_h @ W1h + b1h) ====
__global__ __launch_bounds__(256) void w1_apply(
    const unsigned short* __restrict__ aggb,   // [N,960] bf16, head h at cols h*96
    const unsigned short* __restrict__ W1T,    // [1280,96] bf16
    const float* __restrict__ b1,              // [1280]
    unsigned short* __restrict__ x1)           // [N,1280] bf16
{
    __shared__ __align__(16) unsigned short ls[24576];   // A:[0,12288) B:[12288,24576)
    const int z = blockIdx.y;
    const int row0 = blockIdx.x * 128;
    const int t = threadIdx.x;
    const int wave = t >> 6, lane = t & 63;
    const int wr = (wave >> 1) * 64;
    const int wc = (wave & 1) * 64;
    const int lrow = lane & 15, kg = lane >> 4;

    const unsigned short* A = aggb + (size_t)z * 96;            // lda = 960
    const unsigned short* B = W1T + (size_t)z * 128 * 96;       // ldb = 96

    for (int i = t; i < 1536; i += 256) {
        int r = i / 12, c = i % 12;
        int ks = c >> 2, sl = c & 3;
        int swz = ((sl ^ (r & 3) ^ ((r >> 2) & 3)) * 8);
        uint4 va = *(const uint4*)&A[(size_t)(row0 + r) * 960 + ks * 32 + sl * 8];
        *(uint4*)&ls[(ks * 128 + r) * 32 + swz] = va;
        uint4 vb = *(const uint4*)&B[(size_t)r * 96 + ks * 32 + sl * 8];
        *(uint4*)&ls[12288 + (ks * 128 + r) * 32 + swz] = vb;
    }
    __syncthreads();

    f4_t acc[4][4];
#pragma unroll
    for (int m = 0; m < 4; m++)
#pragma unroll
        for (int n = 0; n < 4; n++) acc[m][n] = (f4_t){0.f, 0.f, 0.f, 0.f};

#pragma unroll
    for (int ks = 0; ks < 3; ks++) {
        frag_t af[4], bfr[4];
#pragma unroll
        for (int m = 0; m < 4; m++) {
            int r = wr + m * 16 + lrow;
            af[m] = *(frag_t*)&ls[(ks * 128 + r) * 32 + ((kg ^ (r & 3) ^ ((r >> 2) & 3)) * 8)];
        }
#pragma unroll
        for (int n = 0; n < 4; n++) {
            int r = wc + n * 16 + lrow;
            bfr[n] = *(frag_t*)&ls[12288 + (ks * 128 + r) * 32 + ((kg ^ (r & 3) ^ ((r >> 2) & 3)) * 8)];
        }
#pragma unroll
        for (int m = 0; m < 4; m++)
#pragma unroll
            for (int n = 0; n < 4; n++)
                acc[m][n] = __builtin_amdgcn_mfma_f32_16x16x32_bf16(af[m], bfr[n], acc[m][n], 0, 0, 0);
    }
    __syncthreads();   // all frag reads done; ls reusable

    // bias + elu, stage bf16 tile [128][128] into ls
#pragma unroll
    for (int m = 0; m < 4; m++) {
#pragma unroll
        for (int n = 0; n < 4; n++) {
            int col = wc + n * 16 + lrow;
            float bv = b1[z * HID + col];
#pragma unroll
            for (int r = 0; r < 4; r++) {
                int lr = wr + m * 16 + kg * 4 + r;
                float v = acc[m][n][r] + bv;
                v = (v > 0.f) ? v : expm1f(v);
                ls[lr * 128 + col] = f2bf(v);
            }
        }
    }
    __syncthreads();

    for (int i = t; i < 2048; i += 256) {
        int r = i >> 4, seg = i & 15;
        *(uint4*)&x1[(size_t)(row0 + r) * F1 + z * HID + seg * 8] =
            *(const uint4*)&ls[r * 128 + seg * 8];
    }
}

// ================= H2 GEMM: double-buffered + fused es2/ed2 + wide store =======
__global__ __launch_bounds__(256) void h2_gemm(
    const unsigned short* __restrict__ A, const unsigned short* __restrict__ BT,
    unsigned short* __restrict__ C,
    const float* __restrict__ as2, const float* __restrict__ ad2,
    float* __restrict__ es2, float* __restrict__ ed2)
{
    __shared__ __align__(16) unsigned short Als[2][32 * 32];
    __shared__ __align__(16) unsigned short Bls[2][128 * 32];
    __shared__ __align__(16) unsigned short ob[32 * 128];
    __shared__ float esl[4][32], edl[4][32];
    const int t = threadIdx.x;
    const int wave = t >> 6, lane = t & 63;
    const int lrow = lane & 15, kg = lane >> 4;
    const int row0 = blockIdx.x * 32;
    const int wc = wave * 32;

    const int ar = t >> 2, asl = t & 3;
    const int br = t >> 2, bsl = t & 3;

    uint4 pa, pb0, pb1;
    auto LOAD = [&](int kk) {
        if (t < 128) pa = *(const uint4*)&A[(size_t)(row0 + ar) * F1 + kk + asl * 8];
        pb0 = *(const uint4*)&BT[(size_t)br * F1 + kk + bsl * 8];
        pb1 = *(const uint4*)&BT[(size_t)(br + 64) * F1 + kk + bsl * 8];
    };
    auto STORE = [&](int buf) {
        if (t < 128)
            *(uint4*)&Als[buf][ar * 32 + ((asl ^ (ar & 3) ^ ((ar >> 2) & 3)) * 8)] = pa;
        *(uint4*)&Bls[buf][br * 32 + ((bsl ^ (br & 3) ^ ((br >> 2) & 3)) * 8)] = pb0;
        int r2 = br + 64;
        *(uint4*)&Bls[buf][r2 * 32 + ((bsl ^ (r2 & 3) ^ ((r2 >> 2) & 3)) * 8)] = pb1;
    };

    LOAD(0);
    STORE(0);
    __syncthreads();

    f4_t acc[2][2];
#pragma unroll
    for (int m = 0; m < 2; m++)
#pragma unroll
        for (int n = 0; n < 2; n++) acc[m][n] = (f4_t){0.f, 0.f, 0.f, 0.f};

    int cur = 0;
    for (int ks = 0; ks < 40; ks++) {
        if (ks < 39) LOAD((ks + 1) * 32);
        frag_t af[2], bfr[2];
#pragma unroll
        for (int m = 0; m < 2; m++) {
            int r = m * 16 + lrow;
            af[m] = *(frag_t*)&Als[cur][r * 32 + ((kg ^ (r & 3) ^ ((r >> 2) & 3)) * 8)];
        }
#pragma unroll
        for (int n = 0; n < 2; n++) {
            int r = wc + n * 16 + lrow;
            bfr[n] = *(frag_t*)&Bls[cur][r * 32 + ((kg ^ (r & 3) ^ ((r >> 2) & 3)) * 8)];
        }
#pragma unroll
        for (int m = 0; m < 2; m++)
#pragma unroll
            for (int n = 0; n < 2; n++)
                acc[m][n] = __builtin_amdgcn_mfma_f32_16x16x32_bf16(af[m], bfr[n], acc[m][n], 0, 0, 0);
        if (ks < 39) STORE(cur ^ 1);
        __syncthreads();
        cur ^= 1;
    }

#pragma unroll
    for (int m = 0; m < 2; m++) {
#pragma unroll
        for (int r = 0; r < 4; r++) {
            int lr = m * 16 + kg * 4 + r;
            float pes = 0.f, ped = 0.f;
#pragma unroll
            for (int n = 0; n < 2; n++) {
                int col = wc + n * 16 + lrow;
                float v = acc[m][n][r];
                ob[lr * 128 + col] = f2bf(v);
                pes = fmaf(v, as2[col], pes);
                ped = fmaf(v, ad2[col], ped);
            }
#pragma unroll
            for (int o = 1; o < 16; o <<= 1) {
                pes += __shfl_xor(pes, o);
                ped += __shfl_xor(ped, o);
            }
            if (lrow == 0) { esl[wave][lr] = pes; edl[wave][lr] = ped; }
        }
    }
    __syncthreads();
    for (int i = t; i < 512; i += 256) {
        int r = i >> 4, seg = i & 15;
        *(uint4*)&C[(size_t)(row0 + r) * HID + seg * 8] = *(const uint4*)&ob[r * 128 + seg * 8];
    }
    if (t < 32) {
        es2[row0 + t] = esl[0][t] + esl[1][t] + esl[2][t] + esl[3][t];
        ed2[row0 + t] = edl[0][t] + edl[1][t] + edl[2][t] + edl[3][t];
    }
}

// ======= pool_head: out[:,0:128] = relu(decode(pk) @ Wg + bg), K=128 in LDS ====
__global__ __launch_bounds__(256) void pool_head(
    const unsigned* __restrict__ pk, const unsigned short* __restrict__ WgT,
    const float* __restrict__ bg, float* __restrict__ out)
{
    __shared__ __align__(16) unsigned short Als[64 * 128];    // 16 KB
    __shared__ __align__(16) unsigned short Bls[128 * 128];   // 32 KB
    const int t = threadIdx.x;
    const int wave = t >> 6, lane = t & 63;
    const int lrow = lane & 15, kg = lane >> 4;
    const int row0 = blockIdx.x * 64;
    const int wr = (wave >> 1) * 32;
    const int wc = (wave & 1) * 64;

    for (int i = t; i < 4096; i += 256) {
        int r = i >> 6, k0 = (i & 63) * 2;
        int ks = k0 >> 5, cw = k0 & 31, slot = cw >> 3, elem = cw & 7;
        unsigned lo = f2bf(funkey(pk[(row0 + r) * HID + k0]));
        unsigned hi = f2bf(funkey(pk[(row0 + r) * HID + k0 + 1]));
        *(unsigned*)&Als[(ks * 64 + r) * 32 + ((slot ^ (r & 3) ^ ((r >> 2) & 3)) * 8) + elem]
            = lo | (hi << 16);
    }
    for (int i = t; i < 2048; i += 256) {
        int r = i >> 4, c = i & 15;
        int ks = c >> 2, sl = c & 3;
        uint4 v = *(const uint4*)&WgT[(size_t)r * HID + ks * 32 + sl * 8];
        *(uint4*)&Bls[(ks * 128 + r) * 32 + ((sl ^ (r & 3) ^ ((r >> 2) & 3)) * 8)] = v;
    }
    __syncthreads();

    f4_t acc[2][4];
#pragma unroll
    for (int m = 0; m < 2; m++)
#pragma unroll
        for (int n = 0; n < 4; n++) acc[m][n] = (f4_t){0.f, 0.f, 0.f, 0.f};

#pragma unroll
    for (int ks = 0; ks < 4; ks++) {
        frag_t af[2], bfr[4];
#pragma unroll
        for (int m = 0; m < 2; m++) {
            int r = wr + m * 16 + lrow;
            af[m] = *(frag_t*)&Als[(ks * 64 + r) * 32 + ((kg ^ (r & 3) ^ ((r >> 2) & 3)) * 8)];
        }
#pragma unroll
        for (int n = 0; n < 4; n++) {
            int r = wc + n * 16 + lrow;
            bfr[n] = *(frag_t*)&Bls[(ks * 128 + r) * 32 + ((kg ^ (r & 3) ^ ((r >> 2) & 3)) * 8)];
        }
#pragma unroll
        for (int m = 0; m < 2; m++)
#pragma unroll
            for (int n = 0; n < 4; n++)
                acc[m][n] = __builtin_amdgcn_mfma_f32_16x16x32_bf16(af[m], bfr[n], acc[m][n], 0, 0, 0);
    }

#pragma unroll
    for (int m = 0; m < 2; m++) {
#pragma unroll
        for (int n = 0; n < 4; n++) {
            int col = wc + n * 16 + lrow;
            float bv = bg[col];
#pragma unroll
            for (int r = 0; r < 4; r++) {
                int row = row0 + wr + m * 16 + kg * 4 + r;
                out[(size_t)row * 130 + col] = fmaxf(acc[m][n][r] + bv, 0.f);
            }
        }
    }
}

// ======= mega prep: xb copy + LDS-TILED transposes + fold + zero-pk + hist + cell
#define NB_XB  6144    // xb: 16384*96/256
#define NB_TRN 836     // 64x64 transpose tiles: W1 40, W2 40, Wf1 480, Wf2 256, Wf3 16, Wg 4
#define NB_FOLD 768    // 3072 fold entries, 4 waves/block
#define NB_ZPK  128    // pk: 32768
#define NB_HIST ((ETOT + 255) / 256)   // 576
#define NB_CELL BGRAPH                 // 256 cell rows

__global__ void prep_all(const float* __restrict__ x,  const float* __restrict__ W1,
                         const float* __restrict__ W2, const float* __restrict__ Wf1,
                         const float* __restrict__ Wf2, const float* __restrict__ Wf3,
                         const float* __restrict__ Wg,
                         const float* __restrict__ as1, const float* __restrict__ ad1,
                         const int* __restrict__ ei, const float* __restrict__ cell,
                         unsigned short* __restrict__ xb,  unsigned short* __restrict__ W1T,
                         unsigned short* __restrict__ W2T, unsigned short* __restrict__ Wf1T,
                         unsigned short* __restrict__ Wf2T, unsigned short* __restrict__ Wf3T,
                         unsigned short* __restrict__ WgT, unsigned short* __restrict__ F1T,
                         int* __restrict__ counts, unsigned* __restrict__ pk,
                         unsigned short* __restrict__ celln)
{
    int blk = blockIdx.x, t = threadIdx.x;
    if (blk < NB_XB) {
        int i = blk * 256 + t;
        int r = i / 96, k = i % 96;
        xb[i] = (k < F_INPUT) ? f2bf(x[r * F_INPUT + k]) : 0;
        return;
    }
    blk -= NB_XB;
    if (blk < NB_TRN) {
        // coalesced 64x64 LDS-tiled transpose: W[k][n] (f32) -> WT[n][k] (bf16)
        const float* src; unsigned short* dst; int ldw, kpad, kreal, kt, nt;
        int b = blk;
        if (b < 40)              { src = W1;  dst = W1T;  ldw = F1;   kpad = KPAD1; kreal = F_INPUT; kt = b % 2;  nt = b / 2;  }
        else if ((b -= 40) < 40) { src = W2;  dst = W2T;  ldw = HID;  kpad = F1;    kreal = F1;      kt = b % 20; nt = b / 20; }
        else if ((b -= 40) < 480){ src = Wf1; dst = Wf1T; ldw = 2048; kpad = KPADC; kreal = F_CELL;  kt = b % 15; nt = b / 15; }
        else if ((b -= 480) < 256){src = Wf2; dst = Wf2T; ldw = 512;  kpad = 2048;  kreal = 2048;    kt = b % 32; nt = b / 32; }
        else if ((b -= 256) < 16){ src = Wf3; dst = Wf3T; ldw = HID;  kpad = 512;   kreal = 512;     kt = b % 8;  nt = b / 8;  }
        else                     { b -= 16; src = Wg; dst = WgT; ldw = HID; kpad = HID; kreal = HID; kt = b % 2;  nt = b / 2;  }
        __shared__ float lsf[64 * 65];   // stride 65: 2-way bank alias (free)
        int c = t & 63, r0 = t >> 6;
        int k0 = kt * 64, n0 = nt * 64;
#pragma unroll
        for (int j = 0; j < 16; j++) {
            int r = r0 * 16 + j;
            int kgl = k0 + r;
            lsf[c * 65 + r] = (kgl < kreal) ? src[(size_t)kgl * ldw + n0 + c] : 0.f;
        }
        __syncthreads();
#pragma unroll
        for (int j = 0; j < 16; j++) {
            int rn = r0 * 16 + j;
            int kk = k0 + c;
            if (kk < kpad)
                dst[(size_t)(n0 + rn) * kpad + kk] = f2bf(lsf[rn * 65 + c]);
        }
        return;
    }
    blk -= NB_TRN;
    if (blk < NB_FOLD) {
        int idx = blk * 4 + (t >> 6);
        int l = t & 63;
        int r = idx / 96, k = idx % 96;
        int sd = r >> 4, h = r & 15;
        float p = 0.f;
        if (h < HEADS && k < F_INPUT) {
            const float* a = (sd ? ad1 : as1) + h * HID;
            float2 wv = *(const float2*)&W1[(size_t)k * F1 + h * HID + 2 * l];
            float2 av = *(const float2*)&a[2 * l];
            p = wv.x * av.x + wv.y * av.y;
#pragma unroll
            for (int o = 32; o > 0; o >>= 1) p += __shfl_xor(p, o);
        }
        if (l == 0) F1T[(size_t)r * 96 + k] = f2bf(p);
        return;
    }
    blk -= NB_FOLD;
    if (blk < NB_ZPK) { pk[blk * 256 + t] = 0; return; }   // 0 < fkey(any float)
    blk -= NB_ZPK;
    if (blk < NB_HIST) {
        int e = blk * 256 + t;
        if (e < ETOT) {
            int dst = (e < E_EDGES) ? ei[E_EDGES + e] : (e - E_EDGES);
            atomicAdd(&counts[dst], 1);
        }
        return;
    }
    blk -= NB_HIST;
    // cell L2-normalize (one block per row)
    {
        int b = blk;
        __shared__ float red[256];
        float s = 0.f;
        for (int c = t; c < F_CELL; c += 256) { float v = cell[(size_t)b * F_CELL + c]; s += v * v; }
        red[t] = s; __syncthreads();
        for (int o = 128; o > 0; o >>= 1) { if (t < o) red[t] += red[t + o]; __syncthreads(); }
        float inv = 1.f / fmaxf(sqrtf(red[0]), 1e-12f);
        for (int c = t; c < KPADC; c += 256) {
            float v = (c < F_CELL) ? cell[(size_t)b * F_CELL + c] * inv : 0.f;
            celln[(size_t)b * KPADC + c] = f2bf(v);
        }
    }
}

// ================= CSR scan (vectorized) + scatter =================
__global__ void scan_counts(const int* __restrict__ counts,
                            int* __restrict__ row_start, int* __restrict__ cursor)
{
    __shared__ int part[256];
    int t = threadIdx.x;
    int base = t * 64;
    int4 v[16];
#pragma unroll
    for (int i = 0; i < 16; i++) v[i] = *(const int4*)&counts[base + i * 4];
    int sum = 0;
#pragma unroll
    for (int i = 0; i < 16; i++) sum += v[i].x + v[i].y + v[i].z + v[i].w;
    part[t] = sum;
    __syncthreads();
    for (int o = 1; o < 256; o <<= 1) {
        int vv = (t >= o) ? part[t - o] : 0;
        __syncthreads();
        part[t] += vv;
        __syncthreads();
    }
    int run = (t == 0) ? 0 : part[t - 1];
#pragma unroll
    for (int i = 0; i < 16; i++) {
        int4 w;
        w.x = run; run += v[i].x;
        w.y = run; run += v[i].y;
        w.z = run; run += v[i].z;
        w.w = run; run += v[i].w;
        *(int4*)&row_start[base + i * 4] = w;
        *(int4*)&cursor[base + i * 4] = w;
    }
    if (t == 255) row_start[N_NODES] = run;
}

__global__ void scatter_csr(const int* __restrict__ ei, int* __restrict__ cursor,
                            int* __restrict__ csr_src)
{
    int e = blockIdx.x * blockDim.x + threadIdx.x;
    if (e >= ETOT) return;
    int src, dst;
    if (e < E_EDGES) { src = ei[e]; dst = ei[E_EDGES + e]; } else { src = dst = e - E_EDGES; }
    int pos = atomicAdd(&cursor[dst], 1);
    csr_src[pos] = src;
}

// ================= GAT layer-1 aggregation over RAW x (96 bf16 per row) ========
__global__ __launch_bounds__(256) void gat1_agg(
    const int* __restrict__ row_start, const int* __restrict__ csr_src,
    const unsigned* __restrict__ xb32,          // [N,48] u32 = 96 bf16
    const float* __restrict__ es, const float* __restrict__ ed,
    unsigned* __restrict__ aggb)                // [N,480] u32 = 960 bf16
{
    const int w = threadIdx.x >> 6, l = threadIdx.x & 63;
    const int n = blockIdx.x * 4 + w;
    const int rs = row_start[n];
    const int deg = row_start[n + 1] - rs;

    __shared__ __align__(16) float w_lds[4][64][12];
    __shared__ int src_lds[4][64];

    float edv[HEADS];
    const float* edp = ed + n * HEADS;
#pragma unroll
    for (int h = 0; h < HEADS; h++) edv[h] = edp[h];

    float acc0[HEADS], acc1[HEADS], den[HEADS];
#pragma unroll
    for (int h = 0; h < HEADS; h++) { acc0[h] = 0.f; acc1[h] = 0.f; den[h] = 0.f; }

    for (int base = 0; base < deg; base += 64) {
        int e = base + l;
        int cnt = min(64, deg - base);
        float wv[HEADS];
        if (e < deg) {
            int s = csr_src[rs + e];
            src_lds[w][l] = s;
            const float* ep = es + s * HEADS;
#pragma unroll
            for (int h = 0; h < HEADS; h++) {
                float v = ep[h] + edv[h];
                v = (v >= 0.f) ? v : NEG_SLOPE * v;
                wv[h] = __expf(v);
            }
        } else {
#pragma unroll
            for (int h = 0; h < HEADS; h++) wv[h] = 0.f;
        }
#pragma unroll
        for (int h = 0; h < HEADS; h++) {
            den[h] += wv[h];
            w_lds[w][l][h] = wv[h];
        }
        asm volatile("" ::: "memory");

        for (int j = 0; j < cnt; j++) {
            int sj = src_lds[w][j];
            unsigned xv = 0;
            if (l < 48) xv = xb32[(size_t)sj * 48 + l];
            float x0 = bf2f((unsigned short)(xv & 0xffffu));
            float x1v = bf2f((unsigned short)(xv >> 16));
            float4 wa = *(const float4*)&w_lds[w][j][0];
            float4 wb = *(const float4*)&w_lds[w][j][4];
            float2 wcv = *(const float2*)&w_lds[w][j][8];
            float ww[HEADS] = {wa.x, wa.y, wa.z, wa.w, wb.x, wb.y, wb.z, wb.w, wcv.x, wcv.y};
#pragma unroll
            for (int h = 0; h < HEADS; h++) {
                acc0[h] = fmaf(ww[h], x0, acc0[h]);
                acc1[h] = fmaf(ww[h], x1v, acc1[h]);
            }
        }
        asm volatile("" ::: "memory");
    }

#pragma unroll
    for (int h = 0; h < HEADS; h++)
#pragma unroll
        for (int o = 32; o > 0; o >>= 1) den[h] += __shfl_xor(den[h], o);

    if (l < 48) {
        unsigned* orow = aggb + (size_t)n * 480;
#pragma unroll
        for (int h = 0; h < HEADS; h++) {
            float inv = 1.f / den[h];
            unsigned lo = f2bf(acc0[h] * inv);
            unsigned hi = f2bf(acc1[h] * inv);
            orow[h * 48 + l] = lo | (hi << 16);
        }
    }
}

// ================= GAT layer-2 aggregation + fused graph max-pool ==============
__global__ __launch_bounds__(256) void gat2_agg(
    const int* __restrict__ row_start, const int* __restrict__ csr_src,
    const unsigned short* __restrict__ H2,
    const float* __restrict__ es, const float* __restrict__ ed,
    const float* __restrict__ b, const int* __restrict__ batch,
    unsigned* __restrict__ pk)
{
    const int w = threadIdx.x >> 6, l = threadIdx.x & 63;
    const int n = blockIdx.x * 4 + w;
    const int rs = row_start[n];
    const int deg = row_start[n + 1] - rs;
    const float edv = ed[n];

    float2 acc = {0.f, 0.f};
    float den = 0.f;
    for (int base = 0; base < deg; base += 64) {
        int e = base + l;
        int cnt = min(64, deg - base);
        int s = 0;
        float wv = 0.f;
        if (e < deg) {
            s = csr_src[rs + e];
            float v = es[s] + edv;
            v = (v >= 0.f) ? v : NEG_SLOPE * v;
            wv = __expf(v);
        }
        den += wv;
        for (int j = 0; j < cnt; j++) {
            float wj = __shfl(wv, j);
            int   sj = __shfl(s, j);
            unsigned hp = *(const unsigned*)&H2[(size_t)sj * HID + 2 * l];
            acc.x = fmaf(wj, bf2f((unsigned short)(hp & 0xffffu)), acc.x);
            acc.y = fmaf(wj, bf2f((unsigned short)(hp >> 16)), acc.y);
        }
    }
#pragma unroll
    for (int o = 32; o > 0; o >>= 1) den += __shfl_xor(den, o);

    float inv = 1.f / den;
    float2 bv = *(const float2*)&b[2 * l];
    float v0 = acc.x * inv + bv.x;
    float v1 = acc.y * inv + bv.y;
    v0 = (v0 > 0.f) ? v0 : expm1f(v0);
    v1 = (v1 > 0.f) ? v1 : expm1f(v1);
    int g = batch[n];
    atomicMax(&pk[g * HID + 2 * l], fkey(v0));
    atomicMax(&pk[g * HID + 2 * l + 1], fkey(v1));
}

extern "C" void kernel_launch(void* const* d_in, const int* in_sizes, int n_in,
                              void* d_out, int out_size, void* d_ws, size_t ws_size,
                              hipStream_t stream)
{
    const float* x    = (const float*)d_in[0];
    const int*   ei   = (const int*)d_in[1];
    const int*   batch= (const int*)d_in[2];
    const float* cell = (const float*)d_in[3];
    const float* W1   = (const float*)d_in[4];
    const float* as1  = (const float*)d_in[5];
    const float* ad1  = (const float*)d_in[6];
    const float* b1   = (const float*)d_in[7];
    const float* W2   = (const float*)d_in[8];
    const float* as2  = (const float*)d_in[9];
    const float* ad2  = (const float*)d_in[10];
    const float* b2   = (const float*)d_in[11];
    const float* Wg   = (const float*)d_in[12];
    const float* bg   = (const float*)d_in[13];
    const float* Wf1  = (const float*)d_in[14];
    const float* bf1  = (const float*)d_in[15];
    const float* Wf2  = (const float*)d_in[16];
    const float* bf2  = (const float*)d_in[17];
    const float* Wf3  = (const float*)d_in[18];
    const float* bf3  = (const float*)d_in[19];
    const float* Wo   = (const float*)d_in[20];
    const float* bo   = (const float*)d_in[21];
    float* out = (float*)d_out;

    char* w = (char*)d_ws;
    auto alloc = [&](size_t bytes) { char* p = w; w += (bytes + 255) & ~(size_t)255; return p; };
    unsigned short* xb   = (unsigned short*)alloc((size_t)N_NODES * KPAD1 * 2);   // 3.1 MB
    unsigned short* W1T  = (unsigned short*)alloc((size_t)F1 * KPAD1 * 2);
    unsigned short* F1T  = (unsigned short*)alloc((size_t)32 * KPAD1 * 2);
    unsigned*       aggb = (unsigned*)alloc((size_t)N_NODES * 480 * 4);           // 31.5 MB
    unsigned short* x1   = (unsigned short*)alloc((size_t)N_NODES * F1 * 2);      // 42 MB
    unsigned short* W2T  = (unsigned short*)alloc((size_t)HID * F1 * 2);
    unsigned short* H2   = (unsigned short*)alloc((size_t)N_NODES * HID * 2);     // 4.2 MB
    float*    es1  = (float*)alloc((size_t)N_NODES * HEADS * 4);
    float*    ed1  = (float*)alloc((size_t)N_NODES * HEADS * 4);
    float*    es2  = (float*)alloc((size_t)N_NODES * 4);
    float*    ed2  = (float*)alloc((size_t)N_NODES * 4);
    int*      counts    = (int*)alloc((size_t)N_NODES * 4);
    int*      row_start = (int*)alloc((size_t)(N_NODES + 1) * 4);
    int*      cursor    = (int*)alloc((size_t)N_NODES * 4);
    int*      csr_src   = (int*)alloc((size_t)ETOT * 4);
    unsigned* pk   = (unsigned*)alloc((size_t)BGRAPH * HID * 4);
    unsigned short* WgT  = (unsigned short*)alloc((size_t)HID * HID * 2);
    unsigned short* celln = (unsigned short*)alloc((size_t)BGRAPH * KPADC * 2);
    unsigned short* Wf1T = (unsigned short*)alloc((size_t)2048 * KPADC * 2);
    unsigned short* Wf2T = (unsigned short*)alloc((size_t)512 * 2048 * 2);
    unsigned short* Wf3T = (unsigned short*)alloc((size_t)HID * 512 * 2);
    unsigned short* xc1b = (unsigned short*)alloc((size_t)BGRAPH * 2048 * 2);
    unsigned short* xc2b = (unsigned short*)alloc((size_t)BGRAPH * 512 * 2);

    dim3 b256(256);

    // 0. zero counts (hist runs inside prep_all)
    hipMemsetAsync(counts, 0, (size_t)N_NODES * 4, stream);

    // 1. all prep: xb copy, tiled transposes, a-fold, zero pk, dst-hist, cell-norm
    prep_all<<<NB_XB + NB_TRN + NB_FOLD + NB_ZPK + NB_HIST + NB_CELL, b256, 0, stream>>>(
        x, W1, W2, Wf1, Wf2, Wf3, Wg, as1, ad1, ei, cell,
        xb, W1T, W2T, Wf1T, Wf2T, Wf3T, WgT, F1T, counts, pk, celln);

    // 2-3. CSR scan + scatter
    scan_counts<<<1, b256, 0, stream>>>(counts, row_start, cursor);
    scatter_csr<<<(ETOT + 255) / 256, b256, 0, stream>>>(ei, cursor, csr_src);

    // 4. layer-1 coefs: es1/ed1 = x @ folded-a  (db pipeline, 256 blocks)
    gemm_db<2, 1, 2, 0, 0><<<dim3(1, N_NODES / 64), b256, 0, stream>>>(
        xb, F1T, nullptr, nullptr, es1, ed1,
        N_NODES, 32, KPAD1, KPAD1, KPAD1, 32, 0, 0, 0, 0);

    // 5. aggregate raw x per head
    gat1_agg<<<N_NODES / 4, b256, 0, stream>>>(row_start, csr_src, (const unsigned*)xb,
                                               es1, ed1, aggb);

    // 6. x1 = elu(agg @ W1 + b1), per head; LDS-wide stores (no write amp)
    w1_apply<<<dim3(N_NODES / 128, HEADS), b256, 0, stream>>>(
        (const unsigned short*)aggb, W1T, b1, x1);

    // 7. H2 = x1 @ W2 (db pipeline) + fused es2/ed2 + wide store
    h2_gemm<<<N_NODES / 32, b256, 0, stream>>>(x1, W2T, H2, as2, ad2, es2, ed2);

    // 8. layer-2 aggregation + fused graph max-pool
    gat2_agg<<<N_NODES / 4, b256, 0, stream>>>(row_start, csr_src, H2, es2, ed2, b2,
                                               batch, pk);

    // 9. out[:,0:128] = relu(decode(pk) @ Wg + bg)  (fused decode + GEMM)
    pool_head<<<BGRAPH / 64, b256, 0, stream>>>(pk, WgT, bg, out);

    // 10-11. cell branch (db pipeline)
    gemm_db<1, 2, 1, 1, 1><<<dim3(2048 / 64, BGRAPH / 32), b256, 0, stream>>>(
        celln, Wf1T, bf1, xc1b, nullptr, nullptr,
        BGRAPH, 2048, KPADC, KPADC, KPADC, 2048, 0, 0, 0, 0);
    gemm_db<1, 2, 1, 1, 1><<<dim3(512 / 64, BGRAPH / 32), b256, 0, stream>>>(
        xc1b, Wf2T, bf2, xc2b, nullptr, nullptr,
        BGRAPH, 512, 2048, 2048, 2048, 512, 0, 0, 0, 0);

    // 12. xc3 = relu(xc2 @ Wf3 + bf3); out[:,128:130] = xc3 @ Wo + bo  (fused)
    mfma_gemm<1, 4, 4, 1, 1><<<dim3(1, BGRAPH / 32), b256, 0, stream>>>(
        xc2b, Wf3T, bf3, out, Wo, bo,
        BGRAPH, HID, 512, 512, 512, 130);
}